// Round 14
// baseline (6838.657 us; speedup 1.0000x reference)
//
#include <hip/hip_runtime.h>
#include <hip/hip_fp16.h>
#include <math.h>

#define NI 64
#define NO 64
#define NH 512
#define NM 64
#define NN 128
#define NB 32
#define NS 256
#define ZD 2048
#define PD 268
#define NG 128         // GEMM blocks
#define GBLK 160       // 32 batch + 128 GEMM
#define TPB 512
#define UPB 4          // hidden units per GEMM block
#define ST 580         // LDS stride for inT rows [b][k]
#define RS_ST 68       // padded stride for r tile (68%32==4)
#define H_ST 68        // padded stride for helper h tile

__device__ __forceinline__ float sigm(float x){ return 1.0f/(1.0f+expf(-x)); }
__device__ __forceinline__ float softplus_(float x){ return (x>15.f)? x : log1pf(expf(x)); }

// ---- coherent (cross-XCD) access helpers: relaxed system-scope = sc0 sc1 ----
__device__ __forceinline__ float cloadf(const float* p){
  return __hip_atomic_load(p, __ATOMIC_RELAXED, __HIP_MEMORY_SCOPE_SYSTEM);
}
__device__ __forceinline__ void cstoref(float* p, float v){
  __hip_atomic_store(p, v, __ATOMIC_RELAXED, __HIP_MEMORY_SCOPE_SYSTEM);
}
__device__ __forceinline__ float2 cloadf2(const float* p){
  unsigned long long u = __hip_atomic_load((const unsigned long long*)p,
                                           __ATOMIC_RELAXED, __HIP_MEMORY_SCOPE_SYSTEM);
  return __builtin_bit_cast(float2, u);
}
__device__ __forceinline__ unsigned long long cload8(const void* p){
  return __hip_atomic_load((const unsigned long long*)p,
                           __ATOMIC_RELAXED, __HIP_MEMORY_SCOPE_SYSTEM);
}
__device__ __forceinline__ void cstore8(void* p, unsigned long long v){
  __hip_atomic_store((unsigned long long*)p, v,
                     __ATOMIC_RELAXED, __HIP_MEMORY_SCOPE_SYSTEM);
}
__device__ __forceinline__ int cloadi(const int* p){
  return __hip_atomic_load(p, __ATOMIC_RELAXED, __HIP_MEMORY_SCOPE_SYSTEM);
}
__device__ __forceinline__ void caddi(int* p){
  __hip_atomic_fetch_add(p, 1, __ATOMIC_RELAXED, __HIP_MEMORY_SCOPE_SYSTEM);
}

// fp16 pack/unpack
__device__ __forceinline__ unsigned long long packh4(float a, float b, float c, float d){
  unsigned short u0 = __builtin_bit_cast(unsigned short, __float2half(a));
  unsigned short u1 = __builtin_bit_cast(unsigned short, __float2half(b));
  unsigned short u2 = __builtin_bit_cast(unsigned short, __float2half(c));
  unsigned short u3 = __builtin_bit_cast(unsigned short, __float2half(d));
  return (unsigned long long)u0 | ((unsigned long long)u1 << 16)
       | ((unsigned long long)u2 << 32) | ((unsigned long long)u3 << 48);
}
__device__ __forceinline__ void unpackh4(unsigned long long v, float* o){
  o[0] = __half2float(__builtin_bit_cast(__half, (unsigned short)(v      )));
  o[1] = __half2float(__builtin_bit_cast(__half, (unsigned short)(v >> 16)));
  o[2] = __half2float(__builtin_bit_cast(__half, (unsigned short)(v >> 32)));
  o[3] = __half2float(__builtin_bit_cast(__half, (unsigned short)(v >> 48)));
}

// ---- single-line atomic counter barrier primitives ----
// post: payload stores drained by __syncthreads (vmcnt0) before the add.
__device__ __forceinline__ void postCnt(int* c){
  __syncthreads();
  if (threadIdx.x == 0) caddi(c);
}
// wait: one lane polls one coherent line; discovery = add + RTT + sleep quantum
__device__ __forceinline__ void waitCnt(const int* c, int target){
  if (threadIdx.x == 0) {
    while (cloadi(c) < target) __builtin_amdgcn_s_sleep(2);
  }
  __syncthreads();
}

struct P1S { float inT[NB*ST]; float zpart[4*16*32]; float rs[NB*RS_ST]; float hx[4*33]; };
struct P2S { float h[8*H_ST]; float pp[544]; };
struct P3S { float h[NH]; float p[PD+4];
             float rk[NM], wk[NM], e[NM], a[NM];
             float sim[NN]; float red[8*64]; float r[NM]; };
union  USH { P1S p1; P2S p2; P3S p3; };

// content+location addressing; 512 threads; mem_s XOR-swizzled:
// logical mem[n][m] at float offset n*64 + (m ^ ((n&7)<<2)).
__device__ void address_head(int t, const float* __restrict__ ks,
                             const float* __restrict__ scal,
                             float* __restrict__ w_arr,
                             const float* __restrict__ mem_s,
                             float* __restrict__ sim_s)
{
  {
    int n = t >> 2, sub = t & 3;
    int cn = (n & 7) << 2;
    float dot = 0.f, sq = 0.f;
#pragma unroll
    for (int i = 0; i < 16; i += 4) {
      int m = sub*16 + i;
      float4 mv = *(const float4*)&mem_s[n*NM + (m ^ cn)];
      float4 kv = *(const float4*)&ks[m];
      dot = fmaf(kv.x, mv.x, dot); dot = fmaf(kv.y, mv.y, dot);
      dot = fmaf(kv.z, mv.z, dot); dot = fmaf(kv.w, mv.w, dot);
      sq  = fmaf(mv.x, mv.x, sq);  sq  = fmaf(mv.y, mv.y, sq);
      sq  = fmaf(mv.z, mv.z, sq);  sq  = fmaf(mv.w, mv.w, sq);
    }
    dot += __shfl_xor(dot, 1); sq += __shfl_xor(sq, 1);
    dot += __shfl_xor(dot, 2); sq += __shfl_xor(sq, 2);
    if (sub == 0) sim_s[n] = dot / (scal[0]*sqrtf(sq) + 1e-8f);
  }
  __syncthreads();
  if (t < 64) {   // wave 0: softmax+gate+shift+sharpen; lane l owns rows l, l+64
    int l = t;
    float beta = scal[1], g = scal[2], s0 = scal[3], s1 = scal[4], s2 = scal[5], gamma = scal[6];
    float x0 = beta*sim_s[l], x1 = beta*sim_s[l+64];
    float mx = fmaxf(x0, x1);
#pragma unroll
    for (int off=32; off; off>>=1) mx = fmaxf(mx, __shfl_xor(mx, off));
    float e0 = expf(x0-mx), e1 = expf(x1-mx);
    float sm = e0+e1;
#pragma unroll
    for (int off=32; off; off>>=1) sm += __shfl_xor(sm, off);
    float inv = 1.0f/sm;
    float wg0 = g*e0*inv + (1.f-g)*w_arr[l];
    float wg1 = g*e1*inv + (1.f-g)*w_arr[l+64];
    float up0 = __shfl(wg0, (l+1)&63);
    float w1f = __shfl(wg1, 0);
    float plus0 = (l==63) ? w1f : up0;
    float dn0 = __shfl(wg0, (l-1)&63);
    float w1b = __shfl(wg1, 63);
    float minus0 = (l==0) ? w1b : dn0;
    float up1 = __shfl(wg1, (l+1)&63);
    float w0f = __shfl(wg0, 0);
    float plus1 = (l==63) ? w0f : up1;
    float dn1 = __shfl(wg1, (l-1)&63);
    float w0b = __shfl(wg0, 63);
    float minus1 = (l==0) ? w0b : dn1;
    float ws0 = s0*plus0 + s1*wg0 + s2*minus0;
    float ws1 = s0*plus1 + s1*wg1 + s2*minus1;
    float wp0 = powf(fmaxf(ws0, 1e-12f), gamma);
    float wp1 = powf(fmaxf(ws1, 1e-12f), gamma);
    float tot = wp0+wp1;
#pragma unroll
    for (int off=32; off; off>>=1) tot += __shfl_xor(tot, off);
    float invt = 1.0f/tot;
    w_arr[l]    = wp0*invt;
    w_arr[l+64] = wp1*invt;
  }
  __syncthreads();
}

extern "C" __global__ __launch_bounds__(TPB, 1)
void ntm_coop(const float* __restrict__ inputs, const float* __restrict__ W_lstm,
              const float* __restrict__ b_lstm, const float* __restrict__ W_int,
              const float* __restrict__ b_int, const float* __restrict__ W_out,
              const float* __restrict__ b_out, float* __restrict__ out,
              float* __restrict__ wsf)
{
  __shared__ float mem_s[NN*NM];          // 32 KB persistent memory (batch blocks)
  __shared__ float wr_s[NN], ww_s[NN];
  __shared__ float scal_s[14];
  __shared__ USH u;

  int*    cnt_h = (int*)wsf;              // 1 line: 128 adds/step (h posted)
  int*    cnt_r = (int*)wsf + 16;         // 1 line: 32 adds/step (r posted)
  int*    cnt_p = (int*)wsf + 32;         // 32 lines @64B: 4 adds/step each (p slices)
  __half* hT16    = (__half*)(wsf + 8192);   // [par][batch][unit] fp16: 2*512*32 halves
  float*  rT    = wsf + 8192 + 16384;     // 32768 halves = 16384 floats
  float*  pT    = rT + NB*NM;             // [batch][c] 32*268
  float*  WrT   = pT + NB*PD;             // [col][k] 2048*64
  float*  WintT = WrT + ZD*64;            // [c][k] 268*512
  float*  WoutT = WintT + PD*NH;          // [c][k] 64*576

  const int t   = threadIdx.x;
  const int bid = blockIdx.x;
  const bool isB = (bid < NB);

  // ---- one-time weight transposes (coherent stores; visibility via counter chains) ----
  {
    int gid = bid*TPB + t;
    for (int idx = gid; idx < PD*NH; idx += GBLK*TPB) {
      int c = idx >> 9, k = idx & 511;
      cstoref(&WintT[idx], W_int[(size_t)k*PD + c]);
    }
    for (int idx = gid; idx < NO*576; idx += GBLK*TPB) {
      int c = idx / 576, k = idx - c*576;
      cstoref(&WoutT[idx], W_out[(size_t)k*NO + c]);
    }
    for (int idx = gid; idx < ZD*64; idx += GBLK*TPB) {
      int c = idx >> 6, k = idx & 63;
      cstoref(&WrT[idx], W_lstm[(size_t)(64 + k)*ZD + c]);
    }
  }

  if (!isB) {
    // ==================== GEMM role (128 blocks) ====================
    const int gb   = bid - NB;
    const int pb_  = t & 31;               // batch lane for GEMM
    const int gate = (t >> 5) & 3;
    const int kp   = t >> 7;               // k-part 0..3
    const int j0   = ((gb & 7) << 6) + ((gb >> 3) * UPB);  // XCD-contiguous cols
    const int colg = gate*NH + j0;
    const int pj   = t >> 5;               // pointwise unit (t<128)
    const int pw   = t & 31;               // pointwise batch
    const int bp   = gb & 31;              // helper: batch
    const int hp   = gb >> 5;              // helper: col range [hp*67, +67)
    float c_reg = 0.f;
    __syncthreads();

    for (int step = 0; step < NS; ++step) {
      const __half* h16_prev = hT16 + (size_t)((step & 1) ^ 1)*NH*NB;
      __half*       h16_cur  = hT16 + (size_t)(step & 1)*NH*NB;

      // ---- stage x(s) and h(s-1) (h visibility: prev-iter waitCnt(cnt_h)) ----
      { int sb = t >> 4, k4 = (t & 15) * 4;
        float4 xv = *(const float4*)(inputs + ((size_t)sb*NS + step)*NI + k4);
        *(float4*)&u.p1.inT[sb*ST + k4] = xv; }
      if (step == 0) {
#pragma unroll
        for (int i = 0; i < 8; ++i) {
          int q = t + 512*i; int b_ = q >> 7, u_ = (q & 127) * 4;
          *(float4*)&u.p1.inT[b_*ST + 64 + u_] = make_float4(0.f,0.f,0.f,0.f);
        }
      } else {
        // fp16 handoff: 8B coherent load = 4 units of one batch
#pragma unroll
        for (int i = 0; i < 8; ++i) {
          int q = t + 512*i; int b_ = q >> 7, u_ = (q & 127) * 4;
          unsigned long long v = cload8(h16_prev + b_*NH + u_);
          float o[4]; unpackh4(v, o);
          *(float4*)&u.p1.inT[b_*ST + 64 + u_] = make_float4(o[0],o[1],o[2],o[3]);
        }
      }
      __syncthreads();

      // ---- z_xh(s): 16 cols x 32 batches ----
      float a0=0.f, a1=0.f, a2=0.f, a3=0.f;
      {
        const float* xr = &u.p1.inT[pb_*ST + kp*16];
        const float* Wp = W_lstm + (size_t)(kp*16)*ZD + colg;
#pragma unroll
        for (int k4 = 0; k4 < 16; k4 += 4) {
          float4 x = *(const float4*)&xr[k4];
          float4 w0 = *(const float4*)(Wp + (size_t)(k4+0)*ZD);
          float4 w1 = *(const float4*)(Wp + (size_t)(k4+1)*ZD);
          float4 w2 = *(const float4*)(Wp + (size_t)(k4+2)*ZD);
          float4 w3 = *(const float4*)(Wp + (size_t)(k4+3)*ZD);
          a0 = fmaf(x.x, w0.x, a0); a1 = fmaf(x.x, w0.y, a1);
          a2 = fmaf(x.x, w0.z, a2); a3 = fmaf(x.x, w0.w, a3);
          a0 = fmaf(x.y, w1.x, a0); a1 = fmaf(x.y, w1.y, a1);
          a2 = fmaf(x.y, w1.z, a2); a3 = fmaf(x.y, w1.w, a3);
          a0 = fmaf(x.z, w2.x, a0); a1 = fmaf(x.z, w2.y, a1);
          a2 = fmaf(x.z, w2.z, a2); a3 = fmaf(x.z, w2.w, a3);
          a0 = fmaf(x.w, w3.x, a0); a1 = fmaf(x.w, w3.y, a1);
          a2 = fmaf(x.w, w3.z, a2); a3 = fmaf(x.w, w3.w, a3);
        }
        const float* hr = &u.p1.inT[pb_*ST + 64 + kp*128];
        const float* Wh = W_lstm + (size_t)(128 + kp*128)*ZD + colg;
#pragma unroll 4
        for (int k4 = 0; k4 < 128; k4 += 4) {
          float4 x = *(const float4*)&hr[k4];
          float4 w0 = *(const float4*)(Wh + (size_t)(k4+0)*ZD);
          float4 w1 = *(const float4*)(Wh + (size_t)(k4+1)*ZD);
          float4 w2 = *(const float4*)(Wh + (size_t)(k4+2)*ZD);
          float4 w3 = *(const float4*)(Wh + (size_t)(k4+3)*ZD);
          a0 = fmaf(x.x, w0.x, a0); a1 = fmaf(x.x, w0.y, a1);
          a2 = fmaf(x.x, w0.z, a2); a3 = fmaf(x.x, w0.w, a3);
          a0 = fmaf(x.y, w1.x, a0); a1 = fmaf(x.y, w1.y, a1);
          a2 = fmaf(x.y, w1.z, a2); a3 = fmaf(x.y, w1.w, a3);
          a0 = fmaf(x.z, w2.x, a0); a1 = fmaf(x.z, w2.y, a1);
          a2 = fmaf(x.z, w2.z, a2); a3 = fmaf(x.z, w2.w, a3);
          a0 = fmaf(x.w, w3.x, a0); a1 = fmaf(x.w, w3.y, a1);
          a2 = fmaf(x.w, w3.z, a2); a3 = fmaf(x.w, w3.w, a3);
        }
        if (step == 0) {   // bake z_r(0) from r_init = 0.01
          const float* Wr0 = W_lstm + (size_t)(64 + kp*16)*ZD + colg;
#pragma unroll
          for (int k = 0; k < 16; ++k) {
            float4 w = *(const float4*)(Wr0 + (size_t)k*ZD);
            a0 = fmaf(0.01f, w.x, a0); a1 = fmaf(0.01f, w.y, a1);
            a2 = fmaf(0.01f, w.z, a2); a3 = fmaf(0.01f, w.w, a3);
          }
        }
      }
      { int base = (kp*16 + gate*4)*32 + pb_;
        u.p1.zpart[base]    = a0;
        u.p1.zpart[base+32] = a1;
        u.p1.zpart[base+64] = a2;
        u.p1.zpart[base+96] = a3; }

      // ---- wait r(s-1), stage to LDS (padded stride) ----
      if (step) {
        waitCnt(cnt_r, 32*step);
        { int e = 2*t; int bb = e >> 6, kk = e & 63;
          float2 v = cloadf2(rT + e);
          *(float2*)&u.p1.rs[bb*RS_ST + kk] = v;
          e += 1024; bb = e >> 6; kk = e & 63;
          v = cloadf2(rT + e);
          *(float2*)&u.p1.rs[bb*RS_ST + kk] = v; }
      }
      __syncthreads();

      // ---- pointwise: z = z_xh + z_r + bias -> c,h (via LDS transpose) ----
      if (t < 128) {
        float zrv[4] = {0.f, 0.f, 0.f, 0.f};
        if (step) {
          const float* rr = &u.p1.rs[pw*RS_ST];
#pragma unroll
          for (int gt = 0; gt < 4; ++gt) {
            const float* Wc = WrT + (size_t)(gt*NH + j0 + pj)*64;
            float acc = 0.f;
#pragma unroll
            for (int k = 0; k < 64; k += 4) {
              float4 w = *(const float4*)&Wc[k];
              acc = fmaf(rr[k],   w.x, acc);
              acc = fmaf(rr[k+1], w.y, acc);
              acc = fmaf(rr[k+2], w.z, acc);
              acc = fmaf(rr[k+3], w.w, acc);
            }
            zrv[gt] = acc;
          }
        }
        float zv[4];
#pragma unroll
        for (int gt = 0; gt < 4; ++gt) {
          int ci = gt*4 + pj;
          zv[gt] = u.p1.zpart[ci*32 + pw] + u.p1.zpart[(16+ci)*32 + pw]
                 + u.p1.zpart[(32+ci)*32 + pw] + u.p1.zpart[(48+ci)*32 + pw]
                 + zrv[gt] + b_lstm[gt*NH + j0 + pj];
        }
        float cn = sigm(zv[1])*c_reg + sigm(zv[0])*tanhf(zv[2]);
        c_reg = cn;
        u.p1.hx[pj*33 + pw] = sigm(zv[3])*tanhf(cn);
      }
      __syncthreads();
      if (t < 32) {   // pack 4 units -> one 8B fp16 store per batch row
        unsigned long long v = packh4(u.p1.hx[t], u.p1.hx[33+t],
                                      u.p1.hx[66+t], u.p1.hx[99+t]);
        cstore8(h16_cur + t*NH + j0, v);
      }
      postCnt(cnt_h);

      // ---- helper: p(s) slice for (batch bp, cols hp*67..+66) ----
      waitCnt(cnt_h, 128*(step+1));
      if (t < 128) {     // 8B packed read, unpack 4 units into padded LDS tile
        unsigned long long v = cload8(h16_cur + bp*NH + 4*t);
        float o[4]; unpackh4(v, o);
        int row = t >> 4, col = (4*t) & 63;
        u.p2.h[row*H_ST + col]   = o[0];
        u.p2.h[row*H_ST + col+1] = o[1];
        u.p2.h[row*H_ST + col+2] = o[2];
        u.p2.h[row*H_ST + col+3] = o[3];
      }
      __syncthreads();
      {
        int c = t >> 3, kc = t & 7;
        const float* Wc = WintT + (size_t)(hp*67 + c)*512 + kc*64;
        const float* hh = &u.p2.h[kc*H_ST];
        float acc = 0.f;
#pragma unroll
        for (int k = 0; k < 64; k += 4) {
          float4 w = *(const float4*)&Wc[k];
          acc = fmaf(hh[k],   w.x, acc);
          acc = fmaf(hh[k+1], w.y, acc);
          acc = fmaf(hh[k+2], w.z, acc);
          acc = fmaf(hh[k+3], w.w, acc);
        }
        u.p2.pp[t] = acc;
        if (t < 24) {                       // tasks 512..535
          int id = 512 + t; int c2 = id >> 3, k2 = id & 7;
          const float* Wc2 = WintT + (size_t)(hp*67 + c2)*512 + k2*64;
          const float* hh2 = &u.p2.h[k2*H_ST];
          float ac2 = 0.f;
#pragma unroll
          for (int k = 0; k < 64; k += 4) {
            float4 w = *(const float4*)&Wc2[k];
            ac2 = fmaf(hh2[k],   w.x, ac2);
            ac2 = fmaf(hh2[k+1], w.y, ac2);
            ac2 = fmaf(hh2[k+2], w.z, ac2);
            ac2 = fmaf(hh2[k+3], w.w, ac2);
          }
          u.p2.pp[id] = ac2;
        }
      }
      __syncthreads();
      if (t < 67) {
        float s8 = 0.f;
#pragma unroll
        for (int q = 0; q < 8; ++q) s8 += u.p2.pp[t*8 + q];
        cstoref(&pT[bp*PD + hp*67 + t], s8);
      }
      postCnt(&cnt_p[bp*16]);
    }
  } else {
    // ==================== batch role (32 blocks) ====================
    const int b = bid;
    for (int i = t; i < NN*NM; i += TPB) mem_s[i] = 0.01f;
    if (t < NN) { wr_s[t] = (t==0)?1.f:0.f; ww_s[t] = (t==0)?1.f:0.f; }
    __syncthreads();

    for (int step = 0; step < NS; ++step) {
      const int era = step + 1;
      const __half* h16_cur = hT16 + (size_t)(step & 1)*NH*NB;

      // ---- wait p(s): single counter (4 helper adds) ----
      waitCnt(&cnt_p[b*16], 4*era);
      if (t < 134) {
        float2 v = cloadf2(pT + b*PD + 2*t);
        u.p3.p[2*t]   = v.x + b_int[2*t];
        u.p3.p[2*t+1] = v.y + b_int[2*t+1];
      }
      // h(s) for the out-GEMV (already posted: cnt_p implies cnt_h chain)
      if (t < 128) {
        unsigned long long v = cload8(h16_cur + b*NH + 4*t);
        float o[4]; unpackh4(v, o);
        *(float4*)&u.p3.h[4*t] = make_float4(o[0],o[1],o[2],o[3]);
      }
      __syncthreads();

      // head params
      if (t < NM) {
        float rk = tanhf(u.p3.p[t]);
        float wk = tanhf(u.p3.p[70+t]);
        u.p3.rk[t] = rk; u.p3.wk[t] = wk;
        u.p3.e[t] = sigm(u.p3.p[140+t]);
        u.p3.a[t] = tanhf(u.p3.p[204+t]);
        float sr = rk*rk, sw = wk*wk;
#pragma unroll
        for (int off=32; off; off>>=1){ sr += __shfl_xor(sr,off); sw += __shfl_xor(sw,off); }
        if (t == 0) { scal_s[0] = sqrtf(sr); scal_s[7] = sqrtf(sw); }
      }
      if (t == 64) {
        scal_s[1] = softplus_(u.p3.p[64]);
        scal_s[2] = sigm(u.p3.p[65]);
        float a0=u.p3.p[66], a1=u.p3.p[67], a2=u.p3.p[68];
        float m = fmaxf(a0,fmaxf(a1,a2));
        float e0=expf(a0-m), e1=expf(a1-m), e2=expf(a2-m);
        float s = e0+e1+e2;
        scal_s[3]=e0/s; scal_s[4]=e1/s; scal_s[5]=e2/s;
        scal_s[6] = 1.f + softplus_(u.p3.p[69]);
      }
      if (t == 128) {
        scal_s[8]  = softplus_(u.p3.p[134]);
        scal_s[9]  = sigm(u.p3.p[135]);
        float a0=u.p3.p[136], a1=u.p3.p[137], a2=u.p3.p[138];
        float m = fmaxf(a0,fmaxf(a1,a2));
        float e0=expf(a0-m), e1=expf(a1-m), e2=expf(a2-m);
        float s = e0+e1+e2;
        scal_s[10]=e0/s; scal_s[11]=e1/s; scal_s[12]=e2/s;
        scal_s[13] = 1.f + softplus_(u.p3.p[139]);
      }
      __syncthreads();

      address_head(t, u.p3.wk, &scal_s[7], ww_s, mem_s, u.p3.sim);

      {  // erase + add
        int n = t >> 2, sub = t & 3;
        int cn = (n & 7) << 2;
        float w = ww_s[n];
#pragma unroll
        for (int i = 0; i < 16; i += 4) {
          int m = sub*16 + i;
          float* mp = &mem_s[n*NM + (m ^ cn)];
          float4 mv = *(float4*)mp;
          float4 ev = *(const float4*)&u.p3.e[m];
          float4 av = *(const float4*)&u.p3.a[m];
          mv.x = mv.x*(1.f - w*ev.x) + w*av.x;
          mv.y = mv.y*(1.f - w*ev.y) + w*av.y;
          mv.z = mv.z*(1.f - w*ev.z) + w*av.z;
          mv.w = mv.w*(1.f - w*ev.w) + w*av.w;
          *(float4*)mp = mv;
        }
      }
      __syncthreads();

      address_head(t, u.p3.rk, &scal_s[0], wr_s, mem_s, u.p3.sim);

      {  // r = w_r @ mem
        int part = t >> 6, m = t & 63;
        float racc = 0.f;
#pragma unroll
        for (int nn = 0; nn < 16; ++nn) {
          int n = part*16 + nn;
          racc = fmaf(wr_s[n], mem_s[n*NM + (m ^ ((n&7)<<2))], racc);
        }
        u.p3.red[part*64 + m] = racc;
      }
      __syncthreads();
      if (t < NM) {
        float rv = 0.f;
#pragma unroll
        for (int pq = 0; pq < 8; ++pq) rv += u.p3.red[pq*64 + t];
        u.p3.r[t] = rv;
        cstoref(&rT[b*NM + t], rv);        // coalesced, 4 lines
      }
      postCnt(cnt_r);                      // r(s) visible -> GEMM can proceed

      // ---- off-path: out(s) = [h, r] @ W_out + b_out ----
      {
        int part = t >> 6, c = t & 63;
        const float* Wc = WoutT + c*576 + part*72;
        float oacc = 0.f;
        int k0 = part*72;
#pragma unroll
        for (int kk = 0; kk < 72; kk += 4) {
          float4 w = *(const float4*)&Wc[kk];
          int k = k0 + kk;
          float v0 = (k   < NH) ? u.p3.h[k]   : u.p3.r[k-NH];
          float v1 = (k+1 < NH) ? u.p3.h[k+1] : u.p3.r[k+1-NH];
          float v2 = (k+2 < NH) ? u.p3.h[k+2] : u.p3.r[k+2-NH];
          float v3 = (k+3 < NH) ? u.p3.h[k+3] : u.p3.r[k+3-NH];
          oacc = fmaf(v0, w.x, oacc);
          oacc = fmaf(v1, w.y, oacc);
          oacc = fmaf(v2, w.z, oacc);
          oacc = fmaf(v3, w.w, oacc);
        }
        u.p3.red[part*64 + c] = oacc;
      }
      __syncthreads();
      if (t < NO) {
        float ov = b_out[t];
#pragma unroll
        for (int pq = 0; pq < 8; ++pq) ov += u.p3.red[pq*64 + t];
        out[(size_t)b*NS*NO + (size_t)step*NO + t] = ov;
      }
      __syncthreads();
    }
  }
}

extern "C" void kernel_launch(void* const* d_in, const int* in_sizes, int n_in,
                              void* d_out, int out_size, void* d_ws, size_t ws_size,
                              hipStream_t stream) {
  const float* inputs = (const float*)d_in[0];
  const float* W_lstm = (const float*)d_in[1];
  const float* b_lstm = (const float*)d_in[2];
  const float* W_int  = (const float*)d_in[3];
  const float* b_int  = (const float*)d_in[4];
  const float* W_out  = (const float*)d_in[5];
  const float* b_out  = (const float*)d_in[6];
  float* outp = (float*)d_out;
  float* wsp  = (float*)d_ws;

  hipMemsetAsync(d_ws, 0, 32768, stream);   // zero cnt_h/cnt_r/cnt_p each launch

  void* args[] = { (void*)&inputs, (void*)&W_lstm, (void*)&b_lstm,
                   (void*)&W_int, (void*)&b_int, (void*)&W_out, (void*)&b_out,
                   (void*)&outp, (void*)&wsp };
  hipLaunchCooperativeKernel((const void*)ntm_coop, dim3(GBLK), dim3(TPB),
                             args, 0, stream);
}

// Round 15
// 6494.061 us; speedup vs baseline: 1.0531x; 1.0531x over previous
//
#include <hip/hip_runtime.h>
#include <hip/hip_fp16.h>
#include <math.h>

#define NI 64
#define NO 64
#define NH 512
#define NM 64
#define NN 128
#define NB 32
#define NS 256
#define ZD 2048
#define PD 268
#define NG 128         // GEMM blocks
#define GBLK 160       // 32 batch + 128 GEMM
#define TPB 512
#define UPB 4          // hidden units per GEMM block
#define ST 580         // LDS stride for inT rows [b][k]
#define RS_ST 68       // padded stride for r tile (68%32==4)
#define PP_ST 272      // padded slice stride for pPart

__device__ __forceinline__ float sigm(float x){ return 1.0f/(1.0f+expf(-x)); }
__device__ __forceinline__ float softplus_(float x){ return (x>15.f)? x : log1pf(expf(x)); }

// ---- coherent (cross-XCD) access helpers: relaxed system-scope = sc0 sc1 ----
__device__ __forceinline__ float cloadf(const float* p){
  return __hip_atomic_load(p, __ATOMIC_RELAXED, __HIP_MEMORY_SCOPE_SYSTEM);
}
__device__ __forceinline__ void cstoref(float* p, float v){
  __hip_atomic_store(p, v, __ATOMIC_RELAXED, __HIP_MEMORY_SCOPE_SYSTEM);
}
__device__ __forceinline__ float2 cloadf2(const float* p){
  unsigned long long u = __hip_atomic_load((const unsigned long long*)p,
                                           __ATOMIC_RELAXED, __HIP_MEMORY_SCOPE_SYSTEM);
  return __builtin_bit_cast(float2, u);
}
__device__ __forceinline__ unsigned long long cload8(const void* p){
  return __hip_atomic_load((const unsigned long long*)p,
                           __ATOMIC_RELAXED, __HIP_MEMORY_SCOPE_SYSTEM);
}
__device__ __forceinline__ void cstore8(void* p, unsigned long long v){
  __hip_atomic_store((unsigned long long*)p, v,
                     __ATOMIC_RELAXED, __HIP_MEMORY_SCOPE_SYSTEM);
}
__device__ __forceinline__ int cloadi(const int* p){
  return __hip_atomic_load(p, __ATOMIC_RELAXED, __HIP_MEMORY_SCOPE_SYSTEM);
}
__device__ __forceinline__ void cstorei(int* p, int v){
  __hip_atomic_store(p, v, __ATOMIC_RELAXED, __HIP_MEMORY_SCOPE_SYSTEM);
}
__device__ __forceinline__ void caddi(int* p){
  __hip_atomic_fetch_add(p, 1, __ATOMIC_RELAXED, __HIP_MEMORY_SCOPE_SYSTEM);
}

// fp16 pack/unpack
__device__ __forceinline__ unsigned long long packh4(float a, float b, float c, float d){
  unsigned short u0 = __builtin_bit_cast(unsigned short, __float2half(a));
  unsigned short u1 = __builtin_bit_cast(unsigned short, __float2half(b));
  unsigned short u2 = __builtin_bit_cast(unsigned short, __float2half(c));
  unsigned short u3 = __builtin_bit_cast(unsigned short, __float2half(d));
  return (unsigned long long)u0 | ((unsigned long long)u1 << 16)
       | ((unsigned long long)u2 << 32) | ((unsigned long long)u3 << 48);
}
__device__ __forceinline__ void unpackh4(unsigned long long v, float* o){
  o[0] = __half2float(__builtin_bit_cast(__half, (unsigned short)(v      )));
  o[1] = __half2float(__builtin_bit_cast(__half, (unsigned short)(v >> 16)));
  o[2] = __half2float(__builtin_bit_cast(__half, (unsigned short)(v >> 32)));
  o[3] = __half2float(__builtin_bit_cast(__half, (unsigned short)(v >> 48)));
}

// ---- barrier primitives ----
__device__ __forceinline__ void postFlag(int* flags, int idx, int era){
  __syncthreads();                        // payload stores drained (vmcnt0)
  if (threadIdx.x == 0) cstorei(&flags[idx*16], era);
}
__device__ __forceinline__ void waitAll32(const int* flags, int era){
  if (threadIdx.x < 32) {
    while (cloadi(&flags[(int)threadIdx.x*16]) < era)
      __builtin_amdgcn_s_sleep(1);
  }
  __syncthreads();
}
__device__ __forceinline__ void postCnt(int* c){
  __syncthreads();                        // payload stores drained (vmcnt0)
  if (threadIdx.x == 0) caddi(c);
}
__device__ __forceinline__ void waitCnt(const int* c, int target){
  if (threadIdx.x == 0) {
    while (cloadi(c) < target) __builtin_amdgcn_s_sleep(2);
  }
  __syncthreads();
}

struct P1S { float inT[NB*ST]; float zpart[4*16*32]; float rs[NB*RS_ST]; float hx[4*33]; };
struct P2S { float h[132]; float pp[544]; };
struct P3S { float h[NH]; float p[PD+4];
             float rk[NM], wk[NM], e[NM], a[NM];
             float sim[NN]; float red[8*64]; float r[NM]; };
union  USH { P1S p1; P2S p2; P3S p3; };

// content+location addressing; 512 threads; mem_s XOR-swizzled:
// logical mem[n][m] at float offset n*64 + (m ^ ((n&7)<<2)).
__device__ void address_head(int t, const float* __restrict__ ks,
                             const float* __restrict__ scal,
                             float* __restrict__ w_arr,
                             const float* __restrict__ mem_s,
                             float* __restrict__ sim_s)
{
  {
    int n = t >> 2, sub = t & 3;
    int cn = (n & 7) << 2;
    float dot = 0.f, sq = 0.f;
#pragma unroll
    for (int i = 0; i < 16; i += 4) {
      int m = sub*16 + i;
      float4 mv = *(const float4*)&mem_s[n*NM + (m ^ cn)];
      float4 kv = *(const float4*)&ks[m];
      dot = fmaf(kv.x, mv.x, dot); dot = fmaf(kv.y, mv.y, dot);
      dot = fmaf(kv.z, mv.z, dot); dot = fmaf(kv.w, mv.w, dot);
      sq  = fmaf(mv.x, mv.x, sq);  sq  = fmaf(mv.y, mv.y, sq);
      sq  = fmaf(mv.z, mv.z, sq);  sq  = fmaf(mv.w, mv.w, sq);
    }
    dot += __shfl_xor(dot, 1); sq += __shfl_xor(sq, 1);
    dot += __shfl_xor(dot, 2); sq += __shfl_xor(sq, 2);
    if (sub == 0) sim_s[n] = dot / (scal[0]*sqrtf(sq) + 1e-8f);
  }
  __syncthreads();
  if (t < 64) {   // wave 0: softmax+gate+shift+sharpen; lane l owns rows l, l+64
    int l = t;
    float beta = scal[1], g = scal[2], s0 = scal[3], s1 = scal[4], s2 = scal[5], gamma = scal[6];
    float x0 = beta*sim_s[l], x1 = beta*sim_s[l+64];
    float mx = fmaxf(x0, x1);
#pragma unroll
    for (int off=32; off; off>>=1) mx = fmaxf(mx, __shfl_xor(mx, off));
    float e0 = expf(x0-mx), e1 = expf(x1-mx);
    float sm = e0+e1;
#pragma unroll
    for (int off=32; off; off>>=1) sm += __shfl_xor(sm, off);
    float inv = 1.0f/sm;
    float wg0 = g*e0*inv + (1.f-g)*w_arr[l];
    float wg1 = g*e1*inv + (1.f-g)*w_arr[l+64];
    float up0 = __shfl(wg0, (l+1)&63);
    float w1f = __shfl(wg1, 0);
    float plus0 = (l==63) ? w1f : up0;
    float dn0 = __shfl(wg0, (l-1)&63);
    float w1b = __shfl(wg1, 63);
    float minus0 = (l==0) ? w1b : dn0;
    float up1 = __shfl(wg1, (l+1)&63);
    float w0f = __shfl(wg0, 0);
    float plus1 = (l==63) ? w0f : up1;
    float dn1 = __shfl(wg1, (l-1)&63);
    float w0b = __shfl(wg0, 63);
    float minus1 = (l==0) ? w0b : dn1;
    float ws0 = s0*plus0 + s1*wg0 + s2*minus0;
    float ws1 = s0*plus1 + s1*wg1 + s2*minus1;
    float wp0 = powf(fmaxf(ws0, 1e-12f), gamma);
    float wp1 = powf(fmaxf(ws1, 1e-12f), gamma);
    float tot = wp0+wp1;
#pragma unroll
    for (int off=32; off; off>>=1) tot += __shfl_xor(tot, off);
    float invt = 1.0f/tot;
    w_arr[l]    = wp0*invt;
    w_arr[l+64] = wp1*invt;
  }
  __syncthreads();
}

extern "C" __global__ __launch_bounds__(TPB, 1)
void ntm_coop(const float* __restrict__ inputs, const float* __restrict__ W_lstm,
              const float* __restrict__ b_lstm, const float* __restrict__ W_int,
              const float* __restrict__ b_int, const float* __restrict__ W_out,
              const float* __restrict__ b_out, float* __restrict__ out,
              float* __restrict__ wsf)
{
  __shared__ float mem_s[NN*NM];          // 32 KB persistent memory (batch blocks)
  __shared__ float wr_s[NN], ww_s[NN];
  __shared__ float scal_s[14];
  __shared__ USH u;

  int*    cbase   = (int*)wsf;            // cnt_g[q] @ [q*16] (q<8); cnt_w @ [256]; cnt_p[b] @ [512+b*16]
  int*    flags_r = (int*)wsf + 1024;     // 32 lines: r(s) posted (era s+1)
  __half* hT16    = (__half*)(wsf + 8192);   // [par][batch][unit] fp16: 2*512*32 halves
  float*  rT    = wsf + 8192 + 16384;     // [batch][m] 32*64
  float*  pPart = rT + NB*NM;             // [par][b][hp][PP_ST] = 2*32*4*272
  float*  WrT   = pPart + 2*NB*4*PP_ST;   // [col][k] 2048*64
  float*  WintT = WrT + ZD*64;            // [c][k] 268*512
  float*  WoutT = WintT + PD*NH;          // [c][k] 64*576

  const int t   = threadIdx.x;
  const int bid = blockIdx.x;
  const bool isB = (bid < NB);

  // ---- one-time weight transposes (all 160 blocks; visibility via cnt_w barrier) ----
  {
    int gid = bid*TPB + t;
    for (int idx = gid; idx < PD*NH; idx += GBLK*TPB) {
      int c = idx >> 9, k = idx & 511;
      cstoref(&WintT[idx], W_int[(size_t)k*PD + c]);
    }
    for (int idx = gid; idx < NO*576; idx += GBLK*TPB) {
      int c = idx / 576, k = idx - c*576;
      cstoref(&WoutT[idx], W_out[(size_t)k*NO + c]);
    }
    for (int idx = gid; idx < ZD*64; idx += GBLK*TPB) {
      int c = idx >> 6, k = idx & 63;
      cstoref(&WrT[idx], W_lstm[(size_t)(64 + k)*ZD + c]);
    }
  }
  postCnt(&cbase[256]);                   // one-time: transposes drained, announce
  waitCnt(&cbase[256], GBLK);             // one-time: all transposes visible

  if (!isB) {
    // ==================== GEMM role (128 blocks) ====================
    const int gb   = bid - NB;
    const int pb_  = t & 31;               // batch lane for GEMM
    const int gate = (t >> 5) & 3;
    const int kp   = t >> 7;               // k-part 0..3
    const int j0   = ((gb & 7) << 6) + ((gb >> 3) * UPB);  // XCD-contiguous cols
    const int colg = gate*NH + j0;
    const int pj   = t >> 5;               // pointwise unit (t<128)
    const int pw   = t & 31;               // pointwise batch
    const int q_g  = gb & 7;               // h-group (16 blocks each)
    const int bp   = gb & 31;              // helper: batch
    const int hp   = gb >> 5;              // helper: k-slice [128hp, +128)
    float c_reg = 0.f;
    __syncthreads();

    for (int step = 0; step < NS; ++step) {
      const __half* h16_prev = hT16 + (size_t)((step & 1) ^ 1)*NH*NB;
      __half*       h16_cur  = hT16 + (size_t)(step & 1)*NH*NB;

      // ---- all h(s-1) visible: 8 group counters, 8 lanes poll 1 line each ----
      if (step) {
        if (t < 8) {
          const int tgt = 16*step;
          while (cloadi(&cbase[t*16]) < tgt) __builtin_amdgcn_s_sleep(1);
        }
        __syncthreads();
      }

      // ---- stage x(s) and h(s-1) ----
      { int sb = t >> 4, k4 = (t & 15) * 4;
        float4 xv = *(const float4*)(inputs + ((size_t)sb*NS + step)*NI + k4);
        *(float4*)&u.p1.inT[sb*ST + k4] = xv; }
      if (step == 0) {
#pragma unroll
        for (int i = 0; i < 8; ++i) {
          int q = t + 512*i; int b_ = q >> 7, u_ = (q & 127) * 4;
          *(float4*)&u.p1.inT[b_*ST + 64 + u_] = make_float4(0.f,0.f,0.f,0.f);
        }
      } else {
#pragma unroll
        for (int i = 0; i < 8; ++i) {
          int q = t + 512*i; int b_ = q >> 7, u_ = (q & 127) * 4;
          unsigned long long v = cload8(h16_prev + b_*NH + u_);
          float o[4]; unpackh4(v, o);
          *(float4*)&u.p1.inT[b_*ST + 64 + u_] = make_float4(o[0],o[1],o[2],o[3]);
        }
      }
      __syncthreads();

      // ---- z_xh(s): 16 cols x 32 batches ----
      float a0=0.f, a1=0.f, a2=0.f, a3=0.f;
      {
        const float* xr = &u.p1.inT[pb_*ST + kp*16];
        const float* Wp = W_lstm + (size_t)(kp*16)*ZD + colg;
#pragma unroll
        for (int k4 = 0; k4 < 16; k4 += 4) {
          float4 x = *(const float4*)&xr[k4];
          float4 w0 = *(const float4*)(Wp + (size_t)(k4+0)*ZD);
          float4 w1 = *(const float4*)(Wp + (size_t)(k4+1)*ZD);
          float4 w2 = *(const float4*)(Wp + (size_t)(k4+2)*ZD);
          float4 w3 = *(const float4*)(Wp + (size_t)(k4+3)*ZD);
          a0 = fmaf(x.x, w0.x, a0); a1 = fmaf(x.x, w0.y, a1);
          a2 = fmaf(x.x, w0.z, a2); a3 = fmaf(x.x, w0.w, a3);
          a0 = fmaf(x.y, w1.x, a0); a1 = fmaf(x.y, w1.y, a1);
          a2 = fmaf(x.y, w1.z, a2); a3 = fmaf(x.y, w1.w, a3);
          a0 = fmaf(x.z, w2.x, a0); a1 = fmaf(x.z, w2.y, a1);
          a2 = fmaf(x.z, w2.z, a2); a3 = fmaf(x.z, w2.w, a3);
          a0 = fmaf(x.w, w3.x, a0); a1 = fmaf(x.w, w3.y, a1);
          a2 = fmaf(x.w, w3.z, a2); a3 = fmaf(x.w, w3.w, a3);
        }
        const float* hr = &u.p1.inT[pb_*ST + 64 + kp*128];
        const float* Wh = W_lstm + (size_t)(128 + kp*128)*ZD + colg;
#pragma unroll 4
        for (int k4 = 0; k4 < 128; k4 += 4) {
          float4 x = *(const float4*)&hr[k4];
          float4 w0 = *(const float4*)(Wh + (size_t)(k4+0)*ZD);
          float4 w1 = *(const float4*)(Wh + (size_t)(k4+1)*ZD);
          float4 w2 = *(const float4*)(Wh + (size_t)(k4+2)*ZD);
          float4 w3 = *(const float4*)(Wh + (size_t)(k4+3)*ZD);
          a0 = fmaf(x.x, w0.x, a0); a1 = fmaf(x.x, w0.y, a1);
          a2 = fmaf(x.x, w0.z, a2); a3 = fmaf(x.x, w0.w, a3);
          a0 = fmaf(x.y, w1.x, a0); a1 = fmaf(x.y, w1.y, a1);
          a2 = fmaf(x.y, w1.z, a2); a3 = fmaf(x.y, w1.w, a3);
          a0 = fmaf(x.z, w2.x, a0); a1 = fmaf(x.z, w2.y, a1);
          a2 = fmaf(x.z, w2.z, a2); a3 = fmaf(x.z, w2.w, a3);
          a0 = fmaf(x.w, w3.x, a0); a1 = fmaf(x.w, w3.y, a1);
          a2 = fmaf(x.w, w3.z, a2); a3 = fmaf(x.w, w3.w, a3);
        }
        if (step == 0) {   // bake z_r(0) from r_init = 0.01
          const float* Wr0 = W_lstm + (size_t)(64 + kp*16)*ZD + colg;
#pragma unroll
          for (int k = 0; k < 16; ++k) {
            float4 w = *(const float4*)(Wr0 + (size_t)k*ZD);
            a0 = fmaf(0.01f, w.x, a0); a1 = fmaf(0.01f, w.y, a1);
            a2 = fmaf(0.01f, w.z, a2); a3 = fmaf(0.01f, w.w, a3);
          }
        }
      }
      { int base = (kp*16 + gate*4)*32 + pb_;
        u.p1.zpart[base]    = a0;
        u.p1.zpart[base+32] = a1;
        u.p1.zpart[base+64] = a2;
        u.p1.zpart[base+96] = a3; }

      // ---- wait r(s-1), stage to LDS ----
      if (step) {
        waitAll32(flags_r, step);
        { int e = 2*t; int bb = e >> 6, kk = e & 63;
          float2 v = cloadf2(rT + e);
          *(float2*)&u.p1.rs[bb*RS_ST + kk] = v;
          e += 1024; bb = e >> 6; kk = e & 63;
          v = cloadf2(rT + e);
          *(float2*)&u.p1.rs[bb*RS_ST + kk] = v; }
      }
      __syncthreads();

      // ---- pointwise: z = z_xh + z_r + bias -> c,h ----
      if (t < 128) {
        float zrv[4] = {0.f, 0.f, 0.f, 0.f};
        if (step) {
          const float* rr = &u.p1.rs[pw*RS_ST];
#pragma unroll
          for (int gt = 0; gt < 4; ++gt) {
            const float* Wc = WrT + (size_t)(gt*NH + j0 + pj)*64;
            float acc = 0.f;
#pragma unroll
            for (int k = 0; k < 64; k += 4) {
              float4 w = *(const float4*)&Wc[k];
              acc = fmaf(rr[k],   w.x, acc);
              acc = fmaf(rr[k+1], w.y, acc);
              acc = fmaf(rr[k+2], w.z, acc);
              acc = fmaf(rr[k+3], w.w, acc);
            }
            zrv[gt] = acc;
          }
        }
        float zv[4];
#pragma unroll
        for (int gt = 0; gt < 4; ++gt) {
          int ci = gt*4 + pj;
          zv[gt] = u.p1.zpart[ci*32 + pw] + u.p1.zpart[(16+ci)*32 + pw]
                 + u.p1.zpart[(32+ci)*32 + pw] + u.p1.zpart[(48+ci)*32 + pw]
                 + zrv[gt] + b_lstm[gt*NH + j0 + pj];
        }
        float cn = sigm(zv[1])*c_reg + sigm(zv[0])*tanhf(zv[2]);
        c_reg = cn;
        u.p1.hx[pj*33 + pw] = sigm(zv[3])*tanhf(cn);
      }
      __syncthreads();
      if (t < 32) {   // pack 4 units -> one 8B fp16 store per batch row
        unsigned long long v = packh4(u.p1.hx[t], u.p1.hx[33+t],
                                      u.p1.hx[66+t], u.p1.hx[99+t]);
        cstore8(h16_cur + t*NH + j0, v);
      }
      postCnt(&cbase[q_g*16]);            // h slice posted -> group counter

      // ---- helper: p k-slice [128hp,+128) for batch bp; needs groups 2hp,2hp+1 ----
      {
        if (t < 2) {
          const int tgt = 16*(step+1);
          while (cloadi(&cbase[(2*hp + t)*16]) < tgt) __builtin_amdgcn_s_sleep(1);
        }
        __syncthreads();
      }
      if (t < 32) {    // read 128-unit h slice (256B coherent)
        unsigned long long v = cload8(h16_cur + bp*NH + hp*128 + 4*t);
        float o[4]; unpackh4(v, o);
        u.p2.h[4*t]   = o[0];
        u.p2.h[4*t+1] = o[1];
        u.p2.h[4*t+2] = o[2];
        u.p2.h[4*t+3] = o[3];
      }
      __syncthreads();
      {  // p_slice[c] over 128 k; 2 threads/col (64 k each)
        int c = t >> 1, kh = t & 1;
        const float* Wc = WintT + (size_t)c*512 + hp*128 + kh*64;
        const float* hh = &u.p2.h[kh*64];
        float acc = 0.f;
#pragma unroll
        for (int k = 0; k < 64; k += 4) {
          float4 w = *(const float4*)&Wc[k];
          acc = fmaf(hh[k],   w.x, acc);
          acc = fmaf(hh[k+1], w.y, acc);
          acc = fmaf(hh[k+2], w.z, acc);
          acc = fmaf(hh[k+3], w.w, acc);
        }
        u.p2.pp[t] = acc;
        if (t < 24) {                      // cols 256..267
          int id = 512 + t; int c2 = id >> 1; int k2 = id & 1;
          const float* Wc2 = WintT + (size_t)c2*512 + hp*128 + k2*64;
          const float* hh2 = &u.p2.h[k2*64];
          float ac2 = 0.f;
#pragma unroll
          for (int k = 0; k < 64; k += 4) {
            float4 w = *(const float4*)&Wc2[k];
            ac2 = fmaf(hh2[k],   w.x, ac2);
            ac2 = fmaf(hh2[k+1], w.y, ac2);
            ac2 = fmaf(hh2[k+2], w.z, ac2);
            ac2 = fmaf(hh2[k+3], w.w, ac2);
          }
          u.p2.pp[id] = ac2;
        }
      }
      __syncthreads();
      if (t < PD) {
        float sv = u.p2.pp[2*t] + u.p2.pp[2*t+1];
        cstoref(&pPart[(((size_t)(step&1)*NB + bp)*4 + hp)*PP_ST + t], sv);
      }
      postCnt(&cbase[512 + bp*16]);       // p slice posted
    }
  } else {
    // ==================== batch role (32 blocks) ====================
    const int b = bid;
    for (int i = t; i < NN*NM; i += TPB) mem_s[i] = 0.01f;
    if (t < NN) { wr_s[t] = (t==0)?1.f:0.f; ww_s[t] = (t==0)?1.f:0.f; }
    __syncthreads();

    for (int step = 0; step < NS; ++step) {
      const int era = step + 1;
      const __half* h16_cur = hT16 + (size_t)(step & 1)*NH*NB;

      // ---- wait p(s): 4 slice posts on one line ----
      waitCnt(&cbase[512 + b*16], 4*era);
      if (t < PD) {
        float pv = b_int[t];
        const float* pb4 = &pPart[(((size_t)(step&1)*NB + b)*4)*PP_ST + t];
#pragma unroll
        for (int hp = 0; hp < 4; ++hp) pv += cloadf(pb4 + hp*PP_ST);
        u.p3.p[t] = pv;
      }
      // h(s) for the out-GEMV (4 slice posts => all 8 groups => all h visible)
      if (t < 128) {
        unsigned long long v = cload8(h16_cur + b*NH + 4*t);
        float o[4]; unpackh4(v, o);
        *(float4*)&u.p3.h[4*t] = make_float4(o[0],o[1],o[2],o[3]);
      }
      __syncthreads();

      // head params
      if (t < NM) {
        float rk = tanhf(u.p3.p[t]);
        float wk = tanhf(u.p3.p[70+t]);
        u.p3.rk[t] = rk; u.p3.wk[t] = wk;
        u.p3.e[t] = sigm(u.p3.p[140+t]);
        u.p3.a[t] = tanhf(u.p3.p[204+t]);
        float sr = rk*rk, sw = wk*wk;
#pragma unroll
        for (int off=32; off; off>>=1){ sr += __shfl_xor(sr,off); sw += __shfl_xor(sw,off); }
        if (t == 0) { scal_s[0] = sqrtf(sr); scal_s[7] = sqrtf(sw); }
      }
      if (t == 64) {
        scal_s[1] = softplus_(u.p3.p[64]);
        scal_s[2] = sigm(u.p3.p[65]);
        float a0=u.p3.p[66], a1=u.p3.p[67], a2=u.p3.p[68];
        float m = fmaxf(a0,fmaxf(a1,a2));
        float e0=expf(a0-m), e1=expf(a1-m), e2=expf(a2-m);
        float s = e0+e1+e2;
        scal_s[3]=e0/s; scal_s[4]=e1/s; scal_s[5]=e2/s;
        scal_s[6] = 1.f + softplus_(u.p3.p[69]);
      }
      if (t == 128) {
        scal_s[8]  = softplus_(u.p3.p[134]);
        scal_s[9]  = sigm(u.p3.p[135]);
        float a0=u.p3.p[136], a1=u.p3.p[137], a2=u.p3.p[138];
        float m = fmaxf(a0,fmaxf(a1,a2));
        float e0=expf(a0-m), e1=expf(a1-m), e2=expf(a2-m);
        float s = e0+e1+e2;
        scal_s[10]=e0/s; scal_s[11]=e1/s; scal_s[12]=e2/s;
        scal_s[13] = 1.f + softplus_(u.p3.p[139]);
      }
      __syncthreads();

      address_head(t, u.p3.wk, &scal_s[7], ww_s, mem_s, u.p3.sim);

      {  // erase + add
        int n = t >> 2, sub = t & 3;
        int cn = (n & 7) << 2;
        float w = ww_s[n];
#pragma unroll
        for (int i = 0; i < 16; i += 4) {
          int m = sub*16 + i;
          float* mp = &mem_s[n*NM + (m ^ cn)];
          float4 mv = *(float4*)mp;
          float4 ev = *(const float4*)&u.p3.e[m];
          float4 av = *(const float4*)&u.p3.a[m];
          mv.x = mv.x*(1.f - w*ev.x) + w*av.x;
          mv.y = mv.y*(1.f - w*ev.y) + w*av.y;
          mv.z = mv.z*(1.f - w*ev.z) + w*av.z;
          mv.w = mv.w*(1.f - w*ev.w) + w*av.w;
          *(float4*)mp = mv;
        }
      }
      __syncthreads();

      address_head(t, u.p3.rk, &scal_s[0], wr_s, mem_s, u.p3.sim);

      {  // r = w_r @ mem
        int part = t >> 6, m = t & 63;
        float racc = 0.f;
#pragma unroll
        for (int nn = 0; nn < 16; ++nn) {
          int n = part*16 + nn;
          racc = fmaf(wr_s[n], mem_s[n*NM + (m ^ ((n&7)<<2))], racc);
        }
        u.p3.red[part*64 + m] = racc;
      }
      __syncthreads();
      if (t < NM) {
        float rv = 0.f;
#pragma unroll
        for (int pq = 0; pq < 8; ++pq) rv += u.p3.red[pq*64 + t];
        u.p3.r[t] = rv;
        cstoref(&rT[b*NM + t], rv);
      }
      postFlag(flags_r, b, era);          // r(s) visible -> GEMM can proceed

      // ---- off-path: out(s) = [h, r] @ W_out + b_out ----
      {
        int part = t >> 6, c = t & 63;
        const float* Wc = WoutT + c*576 + part*72;
        float oacc = 0.f;
        int k0 = part*72;
#pragma unroll
        for (int kk = 0; kk < 72; kk += 4) {
          float4 w = *(const float4*)&Wc[kk];
          int k = k0 + kk;
          float v0 = (k   < NH) ? u.p3.h[k]   : u.p3.r[k-NH];
          float v1 = (k+1 < NH) ? u.p3.h[k+1] : u.p3.r[k+1-NH];
          float v2 = (k+2 < NH) ? u.p3.h[k+2] : u.p3.r[k+2-NH];
          float v3 = (k+3 < NH) ? u.p3.h[k+3] : u.p3.r[k+3-NH];
          oacc = fmaf(v0, w.x, oacc);
          oacc = fmaf(v1, w.y, oacc);
          oacc = fmaf(v2, w.z, oacc);
          oacc = fmaf(v3, w.w, oacc);
        }
        u.p3.red[part*64 + c] = oacc;
      }
      __syncthreads();
      if (t < NO) {
        float ov = b_out[t];
#pragma unroll
        for (int pq = 0; pq < 8; ++pq) ov += u.p3.red[pq*64 + t];
        out[(size_t)b*NS*NO + (size_t)step*NO + t] = ov;
      }
      __syncthreads();
    }
  }
}

extern "C" void kernel_launch(void* const* d_in, const int* in_sizes, int n_in,
                              void* d_out, int out_size, void* d_ws, size_t ws_size,
                              hipStream_t stream) {
  const float* inputs = (const float*)d_in[0];
  const float* W_lstm = (const float*)d_in[1];
  const float* b_lstm = (const float*)d_in[2];
  const float* W_int  = (const float*)d_in[3];
  const float* b_int  = (const float*)d_in[4];
  const float* W_out  = (const float*)d_in[5];
  const float* b_out  = (const float*)d_in[6];
  float* outp = (float*)d_out;
  float* wsp  = (float*)d_ws;

  hipMemsetAsync(d_ws, 0, 32768, stream);   // zero cnt_g/cnt_w/cnt_p/flags_r each launch

  void* args[] = { (void*)&inputs, (void*)&W_lstm, (void*)&b_lstm,
                   (void*)&W_int, (void*)&b_int, (void*)&W_out, (void*)&b_out,
                   (void*)&outp, (void*)&wsp };
  hipLaunchCooperativeKernel((const void*)ntm_coop, dim3(GBLK), dim3(TPB),
                             args, 0, stream);
}

// Round 16
// 5861.747 us; speedup vs baseline: 1.1667x; 1.1079x over previous
//
#include <hip/hip_runtime.h>
#include <hip/hip_fp16.h>
#include <math.h>

#define NI 64
#define NO 64
#define NH 512
#define NM 64
#define NN 128
#define NB 32
#define NS 256
#define ZD 2048
#define PD 268
#define NG 128         // GEMM blocks
#define GBLK 160       // 32 batch + 128 GEMM
#define TPB 512
#define UPB 4          // hidden units per GEMM block
#define ST 580         // LDS stride for inT rows [b][k]
#define RS_ST 68       // padded stride for r tile (68%32==4)

__device__ __forceinline__ float sigm(float x){ return 1.0f/(1.0f+expf(-x)); }
__device__ __forceinline__ float softplus_(float x){ return (x>15.f)? x : log1pf(expf(x)); }

// ---- coherent (cross-XCD) access helpers: relaxed system-scope = sc0 sc1 ----
__device__ __forceinline__ float cloadf(const float* p){
  return __hip_atomic_load(p, __ATOMIC_RELAXED, __HIP_MEMORY_SCOPE_SYSTEM);
}
__device__ __forceinline__ void cstoref(float* p, float v){
  __hip_atomic_store(p, v, __ATOMIC_RELAXED, __HIP_MEMORY_SCOPE_SYSTEM);
}
__device__ __forceinline__ float2 cloadf2(const float* p){
  unsigned long long u = __hip_atomic_load((const unsigned long long*)p,
                                           __ATOMIC_RELAXED, __HIP_MEMORY_SCOPE_SYSTEM);
  return __builtin_bit_cast(float2, u);
}
__device__ __forceinline__ unsigned long long cload8(const void* p){
  return __hip_atomic_load((const unsigned long long*)p,
                           __ATOMIC_RELAXED, __HIP_MEMORY_SCOPE_SYSTEM);
}
__device__ __forceinline__ void cstore8(void* p, unsigned long long v){
  __hip_atomic_store((unsigned long long*)p, v,
                     __ATOMIC_RELAXED, __HIP_MEMORY_SCOPE_SYSTEM);
}
__device__ __forceinline__ int cloadi(const int* p){
  return __hip_atomic_load(p, __ATOMIC_RELAXED, __HIP_MEMORY_SCOPE_SYSTEM);
}
__device__ __forceinline__ void cstorei(int* p, int v){
  __hip_atomic_store(p, v, __ATOMIC_RELAXED, __HIP_MEMORY_SCOPE_SYSTEM);
}
__device__ __forceinline__ void caddi(int* p){
  __hip_atomic_fetch_add(p, 1, __ATOMIC_RELAXED, __HIP_MEMORY_SCOPE_SYSTEM);
}
__device__ __forceinline__ void cstoreh(unsigned short* p, unsigned short v){
  __hip_atomic_store(p, v, __ATOMIC_RELAXED, __HIP_MEMORY_SCOPE_SYSTEM);
}

// fp16 pack/unpack
__device__ __forceinline__ unsigned long long packh4(float a, float b, float c, float d){
  unsigned short u0 = __builtin_bit_cast(unsigned short, __float2half(a));
  unsigned short u1 = __builtin_bit_cast(unsigned short, __float2half(b));
  unsigned short u2 = __builtin_bit_cast(unsigned short, __float2half(c));
  unsigned short u3 = __builtin_bit_cast(unsigned short, __float2half(d));
  return (unsigned long long)u0 | ((unsigned long long)u1 << 16)
       | ((unsigned long long)u2 << 32) | ((unsigned long long)u3 << 48);
}
__device__ __forceinline__ void unpackh4(unsigned long long v, float* o){
  o[0] = __half2float(__builtin_bit_cast(__half, (unsigned short)(v      )));
  o[1] = __half2float(__builtin_bit_cast(__half, (unsigned short)(v >> 16)));
  o[2] = __half2float(__builtin_bit_cast(__half, (unsigned short)(v >> 32)));
  o[3] = __half2float(__builtin_bit_cast(__half, (unsigned short)(v >> 48)));
}

// ---- barrier primitives ----
__device__ __forceinline__ void postFlag(int* flags, int idx, int era){
  __syncthreads();                        // payload stores drained (vmcnt0)
  if (threadIdx.x == 0) cstorei(&flags[idx*16], era);
}
__device__ __forceinline__ void waitAll32(const int* flags, int era){
  if (threadIdx.x < 32) {
    while (cloadi(&flags[(int)threadIdx.x*16]) < era)
      __builtin_amdgcn_s_sleep(1);
  }
  __syncthreads();
}
__device__ __forceinline__ void postCnt(int* c){
  __syncthreads();                        // payload stores drained (vmcnt0)
  if (threadIdx.x == 0) caddi(c);
}
__device__ __forceinline__ void waitCnt(const int* c, int target){
  if (threadIdx.x == 0) {
    while (cloadi(c) < target) __builtin_amdgcn_s_sleep(2);
  }
  __syncthreads();
}

struct P1S { float inT[NB*ST]; float zpart[4*16*32]; float rs[NB*RS_ST]; float hx[4*33]; };
struct P3S { float h[NH]; float pp[544]; float p[PD+4];
             float rk[NM], wk[NM], e[NM], a[NM];
             float sim[NN]; float red[8*64]; float r[NM]; };
union  USH { P1S p1; P3S p3; };

// content+location addressing; 512 threads; mem_s XOR-swizzled:
// logical mem[n][m] at float offset n*64 + (m ^ ((n&7)<<2)).
__device__ void address_head(int t, const float* __restrict__ ks,
                             const float* __restrict__ scal,
                             float* __restrict__ w_arr,
                             const float* __restrict__ mem_s,
                             float* __restrict__ sim_s)
{
  {
    int n = t >> 2, sub = t & 3;
    int cn = (n & 7) << 2;
    float dot = 0.f, sq = 0.f;
#pragma unroll
    for (int i = 0; i < 16; i += 4) {
      int m = sub*16 + i;
      float4 mv = *(const float4*)&mem_s[n*NM + (m ^ cn)];
      float4 kv = *(const float4*)&ks[m];
      dot = fmaf(kv.x, mv.x, dot); dot = fmaf(kv.y, mv.y, dot);
      dot = fmaf(kv.z, mv.z, dot); dot = fmaf(kv.w, mv.w, dot);
      sq  = fmaf(mv.x, mv.x, sq);  sq  = fmaf(mv.y, mv.y, sq);
      sq  = fmaf(mv.z, mv.z, sq);  sq  = fmaf(mv.w, mv.w, sq);
    }
    dot += __shfl_xor(dot, 1); sq += __shfl_xor(sq, 1);
    dot += __shfl_xor(dot, 2); sq += __shfl_xor(sq, 2);
    if (sub == 0) sim_s[n] = dot / (scal[0]*sqrtf(sq) + 1e-8f);
  }
  __syncthreads();
  if (t < 64) {   // wave 0: softmax+gate+shift+sharpen; lane l owns rows l, l+64
    int l = t;
    float beta = scal[1], g = scal[2], s0 = scal[3], s1 = scal[4], s2 = scal[5], gamma = scal[6];
    float x0 = beta*sim_s[l], x1 = beta*sim_s[l+64];
    float mx = fmaxf(x0, x1);
#pragma unroll
    for (int off=32; off; off>>=1) mx = fmaxf(mx, __shfl_xor(mx, off));
    float e0 = expf(x0-mx), e1 = expf(x1-mx);
    float sm = e0+e1;
#pragma unroll
    for (int off=32; off; off>>=1) sm += __shfl_xor(sm, off);
    float inv = 1.0f/sm;
    float wg0 = g*e0*inv + (1.f-g)*w_arr[l];
    float wg1 = g*e1*inv + (1.f-g)*w_arr[l+64];
    float up0 = __shfl(wg0, (l+1)&63);
    float w1f = __shfl(wg1, 0);
    float plus0 = (l==63) ? w1f : up0;
    float dn0 = __shfl(wg0, (l-1)&63);
    float w1b = __shfl(wg1, 63);
    float minus0 = (l==0) ? w1b : dn0;
    float up1 = __shfl(wg1, (l+1)&63);
    float w0f = __shfl(wg0, 0);
    float plus1 = (l==63) ? w0f : up1;
    float dn1 = __shfl(wg1, (l-1)&63);
    float w0b = __shfl(wg0, 63);
    float minus1 = (l==0) ? w0b : dn1;
    float ws0 = s0*plus0 + s1*wg0 + s2*minus0;
    float ws1 = s0*plus1 + s1*wg1 + s2*minus1;
    float wp0 = powf(fmaxf(ws0, 1e-12f), gamma);
    float wp1 = powf(fmaxf(ws1, 1e-12f), gamma);
    float tot = wp0+wp1;
#pragma unroll
    for (int off=32; off; off>>=1) tot += __shfl_xor(tot, off);
    float invt = 1.0f/tot;
    w_arr[l]    = wp0*invt;
    w_arr[l+64] = wp1*invt;
  }
  __syncthreads();
}

extern "C" __global__ __launch_bounds__(TPB, 1)
void ntm_coop(const float* __restrict__ inputs, const float* __restrict__ W_lstm,
              const float* __restrict__ b_lstm, const float* __restrict__ W_int,
              const float* __restrict__ b_int, const float* __restrict__ W_out,
              const float* __restrict__ b_out, float* __restrict__ out,
              float* __restrict__ wsf)
{
  __shared__ float mem_s[NN*NM];          // 32 KB persistent memory (batch blocks)
  __shared__ float wr_s[NN], ww_s[NN];
  __shared__ float scal_s[14];
  __shared__ USH u;

  int*    cbase   = (int*)wsf;            // cnt_g[q] @ [q*16] (q<8); cnt_w @ [256]
  int*    flags_r = (int*)wsf + 1024;     // 32 lines: r(s) posted (era s+1)
  __half* hT16    = (__half*)(wsf + 8192);   // [par][batch][unit] fp16: 2*512*32 halves
  float*  rT      = wsf + 8192 + 16384;   // [batch][m] 32*64
  float*  WrT     = rT + NB*NM;           // [col][k] fp32 2048*64
  unsigned short* WintT16 = (unsigned short*)(WrT + ZD*64);  // [c][k] 268*512 fp16
  unsigned short* WoutT16 = WintT16 + PD*NH;                 // [c][k] 64*576 fp16

  const int t   = threadIdx.x;
  const int bid = blockIdx.x;
  const bool isB = (bid < NB);

  // ---- one-time weight transposes/converts (coherent stores; cnt_w barrier) ----
  {
    int gid = bid*TPB + t;
    for (int idx = gid; idx < PD*NH; idx += GBLK*TPB) {
      int c = idx >> 9, k = idx & 511;
      cstoreh(&WintT16[idx],
              __builtin_bit_cast(unsigned short, __float2half(W_int[(size_t)k*PD + c])));
    }
    for (int idx = gid; idx < NO*576; idx += GBLK*TPB) {
      int c = idx / 576, k = idx - c*576;
      cstoreh(&WoutT16[idx],
              __builtin_bit_cast(unsigned short, __float2half(W_out[(size_t)k*NO + c])));
    }
    for (int idx = gid; idx < ZD*64; idx += GBLK*TPB) {
      int c = idx >> 6, k = idx & 63;
      cstoref(&WrT[idx], W_lstm[(size_t)(64 + k)*ZD + c]);
    }
  }
  postCnt(&cbase[256]);                   // one-time: converts drained
  waitCnt(&cbase[256], GBLK);             // one-time: all converts visible

  if (!isB) {
    // ==================== GEMM role (128 blocks) ====================
    const int gb   = bid - NB;
    const int pb_  = t & 31;               // batch lane for GEMM
    const int gate = (t >> 5) & 3;
    const int kp   = t >> 7;               // k-part 0..3
    const int j0   = ((gb & 7) << 6) + ((gb >> 3) * UPB);  // XCD-contiguous cols
    const int colg = gate*NH + j0;
    const int pj   = t >> 5;               // pointwise unit (t<128)
    const int pw   = t & 31;               // pointwise batch
    const int q_g  = gb & 7;               // h-group (16 blocks each)
    float c_reg = 0.f;
    __syncthreads();

    for (int step = 0; step < NS; ++step) {
      const __half* h16_prev = hT16 + (size_t)((step & 1) ^ 1)*NH*NB;
      __half*       h16_cur  = hT16 + (size_t)(step & 1)*NH*NB;

      // ---- all h(s-1) visible: 8 group counters, 8 lanes poll 1 line each ----
      if (step) {
        if (t < 8) {
          const int tgt = 16*step;
          while (cloadi(&cbase[t*16]) < tgt) __builtin_amdgcn_s_sleep(1);
        }
        __syncthreads();
      }

      // ---- stage x(s) and h(s-1) ----
      { int sb = t >> 4, k4 = (t & 15) * 4;
        float4 xv = *(const float4*)(inputs + ((size_t)sb*NS + step)*NI + k4);
        *(float4*)&u.p1.inT[sb*ST + k4] = xv; }
      if (step == 0) {
#pragma unroll
        for (int i = 0; i < 8; ++i) {
          int q = t + 512*i; int b_ = q >> 7, u_ = (q & 127) * 4;
          *(float4*)&u.p1.inT[b_*ST + 64 + u_] = make_float4(0.f,0.f,0.f,0.f);
        }
      } else {
#pragma unroll
        for (int i = 0; i < 8; ++i) {
          int q = t + 512*i; int b_ = q >> 7, u_ = (q & 127) * 4;
          unsigned long long v = cload8(h16_prev + b_*NH + u_);
          float o[4]; unpackh4(v, o);
          *(float4*)&u.p1.inT[b_*ST + 64 + u_] = make_float4(o[0],o[1],o[2],o[3]);
        }
      }
      __syncthreads();

      // ---- z_xh(s): 16 cols x 32 batches ----
      float a0=0.f, a1=0.f, a2=0.f, a3=0.f;
      {
        const float* xr = &u.p1.inT[pb_*ST + kp*16];
        const float* Wp = W_lstm + (size_t)(kp*16)*ZD + colg;
#pragma unroll
        for (int k4 = 0; k4 < 16; k4 += 4) {
          float4 x = *(const float4*)&xr[k4];
          float4 w0 = *(const float4*)(Wp + (size_t)(k4+0)*ZD);
          float4 w1 = *(const float4*)(Wp + (size_t)(k4+1)*ZD);
          float4 w2 = *(const float4*)(Wp + (size_t)(k4+2)*ZD);
          float4 w3 = *(const float4*)(Wp + (size_t)(k4+3)*ZD);
          a0 = fmaf(x.x, w0.x, a0); a1 = fmaf(x.x, w0.y, a1);
          a2 = fmaf(x.x, w0.z, a2); a3 = fmaf(x.x, w0.w, a3);
          a0 = fmaf(x.y, w1.x, a0); a1 = fmaf(x.y, w1.y, a1);
          a2 = fmaf(x.y, w1.z, a2); a3 = fmaf(x.y, w1.w, a3);
          a0 = fmaf(x.z, w2.x, a0); a1 = fmaf(x.z, w2.y, a1);
          a2 = fmaf(x.z, w2.z, a2); a3 = fmaf(x.z, w2.w, a3);
          a0 = fmaf(x.w, w3.x, a0); a1 = fmaf(x.w, w3.y, a1);
          a2 = fmaf(x.w, w3.z, a2); a3 = fmaf(x.w, w3.w, a3);
        }
        const float* hr = &u.p1.inT[pb_*ST + 64 + kp*128];
        const float* Wh = W_lstm + (size_t)(128 + kp*128)*ZD + colg;
#pragma unroll 4
        for (int k4 = 0; k4 < 128; k4 += 4) {
          float4 x = *(const float4*)&hr[k4];
          float4 w0 = *(const float4*)(Wh + (size_t)(k4+0)*ZD);
          float4 w1 = *(const float4*)(Wh + (size_t)(k4+1)*ZD);
          float4 w2 = *(const float4*)(Wh + (size_t)(k4+2)*ZD);
          float4 w3 = *(const float4*)(Wh + (size_t)(k4+3)*ZD);
          a0 = fmaf(x.x, w0.x, a0); a1 = fmaf(x.x, w0.y, a1);
          a2 = fmaf(x.x, w0.z, a2); a3 = fmaf(x.x, w0.w, a3);
          a0 = fmaf(x.y, w1.x, a0); a1 = fmaf(x.y, w1.y, a1);
          a2 = fmaf(x.y, w1.z, a2); a3 = fmaf(x.y, w1.w, a3);
          a0 = fmaf(x.z, w2.x, a0); a1 = fmaf(x.z, w2.y, a1);
          a2 = fmaf(x.z, w2.z, a2); a3 = fmaf(x.z, w2.w, a3);
          a0 = fmaf(x.w, w3.x, a0); a1 = fmaf(x.w, w3.y, a1);
          a2 = fmaf(x.w, w3.z, a2); a3 = fmaf(x.w, w3.w, a3);
        }
        if (step == 0) {   // bake z_r(0) from r_init = 0.01
          const float* Wr0 = W_lstm + (size_t)(64 + kp*16)*ZD + colg;
#pragma unroll
          for (int k = 0; k < 16; ++k) {
            float4 w = *(const float4*)(Wr0 + (size_t)k*ZD);
            a0 = fmaf(0.01f, w.x, a0); a1 = fmaf(0.01f, w.y, a1);
            a2 = fmaf(0.01f, w.z, a2); a3 = fmaf(0.01f, w.w, a3);
          }
        }
      }
      { int base = (kp*16 + gate*4)*32 + pb_;
        u.p1.zpart[base]    = a0;
        u.p1.zpart[base+32] = a1;
        u.p1.zpart[base+64] = a2;
        u.p1.zpart[base+96] = a3; }

      // ---- wait r(s-1), stage to LDS ----
      if (step) {
        waitAll32(flags_r, step);
        { int e = 2*t; int bb = e >> 6, kk = e & 63;
          float2 v = cloadf2(rT + e);
          *(float2*)&u.p1.rs[bb*RS_ST + kk] = v;
          e += 1024; bb = e >> 6; kk = e & 63;
          v = cloadf2(rT + e);
          *(float2*)&u.p1.rs[bb*RS_ST + kk] = v; }
      }
      __syncthreads();

      // ---- pointwise: z = z_xh + z_r + bias -> c,h ----
      if (t < 128) {
        float zrv[4] = {0.f, 0.f, 0.f, 0.f};
        if (step) {
          const float* rr = &u.p1.rs[pw*RS_ST];
#pragma unroll
          for (int gt = 0; gt < 4; ++gt) {
            const float* Wc = WrT + (size_t)(gt*NH + j0 + pj)*64;
            float acc = 0.f;
#pragma unroll
            for (int k = 0; k < 64; k += 4) {
              float4 w = *(const float4*)&Wc[k];
              acc = fmaf(rr[k],   w.x, acc);
              acc = fmaf(rr[k+1], w.y, acc);
              acc = fmaf(rr[k+2], w.z, acc);
              acc = fmaf(rr[k+3], w.w, acc);
            }
            zrv[gt] = acc;
          }
        }
        float zv[4];
#pragma unroll
        for (int gt = 0; gt < 4; ++gt) {
          int ci = gt*4 + pj;
          zv[gt] = u.p1.zpart[ci*32 + pw] + u.p1.zpart[(16+ci)*32 + pw]
                 + u.p1.zpart[(32+ci)*32 + pw] + u.p1.zpart[(48+ci)*32 + pw]
                 + zrv[gt] + b_lstm[gt*NH + j0 + pj];
        }
        float cn = sigm(zv[1])*c_reg + sigm(zv[0])*tanhf(zv[2]);
        c_reg = cn;
        u.p1.hx[pj*33 + pw] = sigm(zv[3])*tanhf(cn);
      }
      __syncthreads();
      if (t < 32) {   // pack 4 units -> one 8B fp16 store per batch row
        unsigned long long v = packh4(u.p1.hx[t], u.p1.hx[33+t],
                                      u.p1.hx[66+t], u.p1.hx[99+t]);
        cstore8(h16_cur + t*NH + j0, v);
      }
      postCnt(&cbase[q_g*16]);            // h slice posted -> group counter
    }
  } else {
    // ==================== batch role (32 blocks) ====================
    const int b = bid;
    for (int i = t; i < NN*NM; i += TPB) mem_s[i] = 0.01f;
    if (t < NN) { wr_s[t] = (t==0)?1.f:0.f; ww_s[t] = (t==0)?1.f:0.f; }
    __syncthreads();

    for (int step = 0; step < NS; ++step) {
      const int era = step + 1;
      const __half* h16_cur = hT16 + (size_t)(step & 1)*NH*NB;

      // ---- wait all h(s): 8 group counters ----
      if (t < 8) {
        const int tgt = 16*era;
        while (cloadi(&cbase[t*16]) < tgt) __builtin_amdgcn_s_sleep(1);
      }
      __syncthreads();

      // ---- read own h row (coalesced coherent, 1 KB) ----
      if (t < 128) {
        unsigned long long v = cload8(h16_cur + b*NH + 4*t);
        float o[4]; unpackh4(v, o);
        *(float4*)&u.p3.h[4*t] = make_float4(o[0],o[1],o[2],o[3]);
      }
      __syncthreads();

      // ---- p = h @ W_int + b_int (fp16 weights, plain loads, XCD-L2 resident) ----
      {
        int c = t >> 1, kh = t & 1;
        const unsigned long long* Wc =
            (const unsigned long long*)(WintT16 + (size_t)c*512 + kh*256);
        const float* hh = u.p3.h + kh*256;
        float pacc = 0.f;
#pragma unroll 8
        for (int k = 0; k < 256; k += 4) {
          float o[4]; unpackh4(Wc[k >> 2], o);
          pacc = fmaf(hh[k],   o[0], pacc);
          pacc = fmaf(hh[k+1], o[1], pacc);
          pacc = fmaf(hh[k+2], o[2], pacc);
          pacc = fmaf(hh[k+3], o[3], pacc);
        }
        u.p3.pp[t] = pacc;
        if (t < 24) {
          int id = 512 + t; int c2 = id >> 1; int k2 = id & 1;
          const unsigned long long* Wc2 =
              (const unsigned long long*)(WintT16 + (size_t)c2*512 + k2*256);
          const float* hh2 = u.p3.h + k2*256;
          float pa2 = 0.f;
#pragma unroll 8
          for (int k = 0; k < 256; k += 4) {
            float o[4]; unpackh4(Wc2[k >> 2], o);
            pa2 = fmaf(hh2[k],   o[0], pa2);
            pa2 = fmaf(hh2[k+1], o[1], pa2);
            pa2 = fmaf(hh2[k+2], o[2], pa2);
            pa2 = fmaf(hh2[k+3], o[3], pa2);
          }
          u.p3.pp[id] = pa2;
        }
      }
      __syncthreads();
      if (t < PD) u.p3.p[t] = u.p3.pp[2*t] + u.p3.pp[2*t+1] + b_int[t];
      __syncthreads();

      // head params
      if (t < NM) {
        float rk = tanhf(u.p3.p[t]);
        float wk = tanhf(u.p3.p[70+t]);
        u.p3.rk[t] = rk; u.p3.wk[t] = wk;
        u.p3.e[t] = sigm(u.p3.p[140+t]);
        u.p3.a[t] = tanhf(u.p3.p[204+t]);
        float sr = rk*rk, sw = wk*wk;
#pragma unroll
        for (int off=32; off; off>>=1){ sr += __shfl_xor(sr,off); sw += __shfl_xor(sw,off); }
        if (t == 0) { scal_s[0] = sqrtf(sr); scal_s[7] = sqrtf(sw); }
      }
      if (t == 64) {
        scal_s[1] = softplus_(u.p3.p[64]);
        scal_s[2] = sigm(u.p3.p[65]);
        float a0=u.p3.p[66], a1=u.p3.p[67], a2=u.p3.p[68];
        float m = fmaxf(a0,fmaxf(a1,a2));
        float e0=expf(a0-m), e1=expf(a1-m), e2=expf(a2-m);
        float s = e0+e1+e2;
        scal_s[3]=e0/s; scal_s[4]=e1/s; scal_s[5]=e2/s;
        scal_s[6] = 1.f + softplus_(u.p3.p[69]);
      }
      if (t == 128) {
        scal_s[8]  = softplus_(u.p3.p[134]);
        scal_s[9]  = sigm(u.p3.p[135]);
        float a0=u.p3.p[136], a1=u.p3.p[137], a2=u.p3.p[138];
        float m = fmaxf(a0,fmaxf(a1,a2));
        float e0=expf(a0-m), e1=expf(a1-m), e2=expf(a2-m);
        float s = e0+e1+e2;
        scal_s[10]=e0/s; scal_s[11]=e1/s; scal_s[12]=e2/s;
        scal_s[13] = 1.f + softplus_(u.p3.p[139]);
      }
      __syncthreads();

      address_head(t, u.p3.wk, &scal_s[7], ww_s, mem_s, u.p3.sim);

      {  // erase + add
        int n = t >> 2, sub = t & 3;
        int cn = (n & 7) << 2;
        float w = ww_s[n];
#pragma unroll
        for (int i = 0; i < 16; i += 4) {
          int m = sub*16 + i;
          float* mp = &mem_s[n*NM + (m ^ cn)];
          float4 mv = *(float4*)mp;
          float4 ev = *(const float4*)&u.p3.e[m];
          float4 av = *(const float4*)&u.p3.a[m];
          mv.x = mv.x*(1.f - w*ev.x) + w*av.x;
          mv.y = mv.y*(1.f - w*ev.y) + w*av.y;
          mv.z = mv.z*(1.f - w*ev.z) + w*av.z;
          mv.w = mv.w*(1.f - w*ev.w) + w*av.w;
          *(float4*)mp = mv;
        }
      }
      __syncthreads();

      address_head(t, u.p3.rk, &scal_s[0], wr_s, mem_s, u.p3.sim);

      {  // r = w_r @ mem
        int part = t >> 6, m = t & 63;
        float racc = 0.f;
#pragma unroll
        for (int nn = 0; nn < 16; ++nn) {
          int n = part*16 + nn;
          racc = fmaf(wr_s[n], mem_s[n*NM + (m ^ ((n&7)<<2))], racc);
        }
        u.p3.red[part*64 + m] = racc;
      }
      __syncthreads();
      if (t < NM) {
        float rv = 0.f;
#pragma unroll
        for (int pq = 0; pq < 8; ++pq) rv += u.p3.red[pq*64 + t];
        u.p3.r[t] = rv;
        cstoref(&rT[b*NM + t], rv);
      }
      postFlag(flags_r, b, era);          // r(s) visible -> GEMM can proceed

      // ---- off-path: out(s) = [h, r] @ W_out + b_out (fp16 weights) ----
      {
        int part = t >> 6, c = t & 63;
        const unsigned long long* Wc =
            (const unsigned long long*)(WoutT16 + (size_t)c*576 + part*72);
        float oacc = 0.f;
        int k0 = part*72;
#pragma unroll
        for (int kk = 0; kk < 72; kk += 4) {
          float o[4]; unpackh4(Wc[kk >> 2], o);
          int k = k0 + kk;
          float v0 = (k   < NH) ? u.p3.h[k]   : u.p3.r[k-NH];
          float v1 = (k+1 < NH) ? u.p3.h[k+1] : u.p3.r[k+1-NH];
          float v2 = (k+2 < NH) ? u.p3.h[k+2] : u.p3.r[k+2-NH];
          float v3 = (k+3 < NH) ? u.p3.h[k+3] : u.p3.r[k+3-NH];
          oacc = fmaf(v0, o[0], oacc);
          oacc = fmaf(v1, o[1], oacc);
          oacc = fmaf(v2, o[2], oacc);
          oacc = fmaf(v3, o[3], oacc);
        }
        u.p3.red[part*64 + c] = oacc;
      }
      __syncthreads();
      if (t < NO) {
        float ov = b_out[t];
#pragma unroll
        for (int pq = 0; pq < 8; ++pq) ov += u.p3.red[pq*64 + t];
        out[(size_t)b*NS*NO + (size_t)step*NO + t] = ov;
      }
      __syncthreads();
    }
  }
}

extern "C" void kernel_launch(void* const* d_in, const int* in_sizes, int n_in,
                              void* d_out, int out_size, void* d_ws, size_t ws_size,
                              hipStream_t stream) {
  const float* inputs = (const float*)d_in[0];
  const float* W_lstm = (const float*)d_in[1];
  const float* b_lstm = (const float*)d_in[2];
  const float* W_int  = (const float*)d_in[3];
  const float* b_int  = (const float*)d_in[4];
  const float* W_out  = (const float*)d_in[5];
  const float* b_out  = (const float*)d_in[6];
  float* outp = (float*)d_out;
  float* wsp  = (float*)d_ws;

  hipMemsetAsync(d_ws, 0, 32768, stream);   // zero cnt_g/cnt_w/flags_r each launch

  void* args[] = { (void*)&inputs, (void*)&W_lstm, (void*)&b_lstm,
                   (void*)&W_int, (void*)&b_int, (void*)&W_out, (void*)&b_out,
                   (void*)&outp, (void*)&wsp };
  hipLaunchCooperativeKernel((const void*)ntm_coop, dim3(GBLK), dim3(TPB),
                             args, 0, stream);
}

// Round 17
// 5430.425 us; speedup vs baseline: 1.2593x; 1.0794x over previous
//
#include <hip/hip_runtime.h>
#include <hip/hip_fp16.h>
#include <math.h>

#define NI 64
#define NO 64
#define NH 512
#define NM 64
#define NN 128
#define NB 32
#define NS 256
#define ZD 2048
#define PD 268
#define NG 128         // GEMM blocks
#define GBLK 160       // 32 batch + 128 GEMM
#define TPB 512
#define UPB 4          // hidden units per GEMM block
#define ST 580         // LDS stride for inT rows [b][k]
#define RS_ST 68       // padded stride for r tile (68%32==4)

// ---- fast transcendentals (v_exp/v_log based; rel err ~1e-5, inputs bounded) ----
__device__ __forceinline__ float fexp(float x){ return __expf(x); }
__device__ __forceinline__ float sigm(float x){ return 1.0f/(1.0f+__expf(-x)); }
__device__ __forceinline__ float ftanh(float x){
  // tanh(x) = 1 - 2/(exp(2x)+1); saturate |x|>10
  float e = __expf(2.f*x);
  return (x > 10.f) ? 1.f : (x < -10.f) ? -1.f : (e - 1.f)/(e + 1.f);
}
__device__ __forceinline__ float softplus_(float x){
  return (x > 15.f) ? x : __logf(1.f + __expf(x));
}
__device__ __forceinline__ float fpow_(float x, float g){   // x>0
  return __expf(g*__logf(x));
}

// ---- coherent (cross-XCD) access helpers: relaxed system-scope = sc0 sc1 ----
__device__ __forceinline__ float cloadf(const float* p){
  return __hip_atomic_load(p, __ATOMIC_RELAXED, __HIP_MEMORY_SCOPE_SYSTEM);
}
__device__ __forceinline__ void cstoref(float* p, float v){
  __hip_atomic_store(p, v, __ATOMIC_RELAXED, __HIP_MEMORY_SCOPE_SYSTEM);
}
__device__ __forceinline__ float2 cloadf2(const float* p){
  unsigned long long u = __hip_atomic_load((const unsigned long long*)p,
                                           __ATOMIC_RELAXED, __HIP_MEMORY_SCOPE_SYSTEM);
  return __builtin_bit_cast(float2, u);
}
__device__ __forceinline__ unsigned long long cload8(const void* p){
  return __hip_atomic_load((const unsigned long long*)p,
                           __ATOMIC_RELAXED, __HIP_MEMORY_SCOPE_SYSTEM);
}
__device__ __forceinline__ void cstore8(void* p, unsigned long long v){
  __hip_atomic_store((unsigned long long*)p, v,
                     __ATOMIC_RELAXED, __HIP_MEMORY_SCOPE_SYSTEM);
}
__device__ __forceinline__ int cloadi(const int* p){
  return __hip_atomic_load(p, __ATOMIC_RELAXED, __HIP_MEMORY_SCOPE_SYSTEM);
}
__device__ __forceinline__ void cstorei(int* p, int v){
  __hip_atomic_store(p, v, __ATOMIC_RELAXED, __HIP_MEMORY_SCOPE_SYSTEM);
}
__device__ __forceinline__ void caddi(int* p){
  __hip_atomic_fetch_add(p, 1, __ATOMIC_RELAXED, __HIP_MEMORY_SCOPE_SYSTEM);
}
__device__ __forceinline__ void cstoreh(unsigned short* p, unsigned short v){
  __hip_atomic_store(p, v, __ATOMIC_RELAXED, __HIP_MEMORY_SCOPE_SYSTEM);
}

// fp16 pack/unpack
__device__ __forceinline__ unsigned long long packh4(float a, float b, float c, float d){
  unsigned short u0 = __builtin_bit_cast(unsigned short, __float2half(a));
  unsigned short u1 = __builtin_bit_cast(unsigned short, __float2half(b));
  unsigned short u2 = __builtin_bit_cast(unsigned short, __float2half(c));
  unsigned short u3 = __builtin_bit_cast(unsigned short, __float2half(d));
  return (unsigned long long)u0 | ((unsigned long long)u1 << 16)
       | ((unsigned long long)u2 << 32) | ((unsigned long long)u3 << 48);
}
__device__ __forceinline__ void unpackh4(unsigned long long v, float* o){
  o[0] = __half2float(__builtin_bit_cast(__half, (unsigned short)(v      )));
  o[1] = __half2float(__builtin_bit_cast(__half, (unsigned short)(v >> 16)));
  o[2] = __half2float(__builtin_bit_cast(__half, (unsigned short)(v >> 32)));
  o[3] = __half2float(__builtin_bit_cast(__half, (unsigned short)(v >> 48)));
}

// ---- barrier primitives ----
__device__ __forceinline__ void postFlag(int* flags, int idx, int era){
  __syncthreads();                        // payload stores drained (vmcnt0)
  if (threadIdx.x == 0) cstorei(&flags[idx*16], era);
}
__device__ __forceinline__ void waitAll32(const int* flags, int era){
  if (threadIdx.x < 32) {
    while (cloadi(&flags[(int)threadIdx.x*16]) < era)
      __builtin_amdgcn_s_sleep(1);
  }
  __syncthreads();
}
__device__ __forceinline__ void postCnt(int* c){
  __syncthreads();                        // payload stores drained (vmcnt0)
  if (threadIdx.x == 0) caddi(c);
}
__device__ __forceinline__ void waitCnt(const int* c, int target){
  if (threadIdx.x == 0) {
    while (cloadi(c) < target) __builtin_amdgcn_s_sleep(2);
  }
  __syncthreads();
}

struct P1S { float inT[NB*ST]; float zpart[4*16*32]; float rs[NB*RS_ST]; float hx[4*33]; };
struct P3S { float h[NH]; float pp[544]; float p[PD+4];
             float rk[NM], wk[NM], e[NM], a[NM];
             float sim[NN]; float red[8*64]; float r[NM]; };
union  USH { P1S p1; P3S p3; };

// content+location addressing; 512 threads; mem_s XOR-swizzled:
// logical mem[n][m] at float offset n*64 + (m ^ ((n&7)<<2)).
__device__ void address_head(int t, const float* __restrict__ ks,
                             const float* __restrict__ scal,
                             float* __restrict__ w_arr,
                             const float* __restrict__ mem_s,
                             float* __restrict__ sim_s)
{
  {
    int n = t >> 2, sub = t & 3;
    int cn = (n & 7) << 2;
    float dot = 0.f, sq = 0.f;
#pragma unroll
    for (int i = 0; i < 16; i += 4) {
      int m = sub*16 + i;
      float4 mv = *(const float4*)&mem_s[n*NM + (m ^ cn)];
      float4 kv = *(const float4*)&ks[m];
      dot = fmaf(kv.x, mv.x, dot); dot = fmaf(kv.y, mv.y, dot);
      dot = fmaf(kv.z, mv.z, dot); dot = fmaf(kv.w, mv.w, dot);
      sq  = fmaf(mv.x, mv.x, sq);  sq  = fmaf(mv.y, mv.y, sq);
      sq  = fmaf(mv.z, mv.z, sq);  sq  = fmaf(mv.w, mv.w, sq);
    }
    dot += __shfl_xor(dot, 1); sq += __shfl_xor(sq, 1);
    dot += __shfl_xor(dot, 2); sq += __shfl_xor(sq, 2);
    if (sub == 0) sim_s[n] = dot / (scal[0]*sqrtf(sq) + 1e-8f);
  }
  __syncthreads();
  if (t < 64) {   // wave 0: softmax+gate+shift+sharpen; lane l owns rows l, l+64
    int l = t;
    float beta = scal[1], g = scal[2], s0 = scal[3], s1 = scal[4], s2 = scal[5], gamma = scal[6];
    float x0 = beta*sim_s[l], x1 = beta*sim_s[l+64];
    float mx = fmaxf(x0, x1);
#pragma unroll
    for (int off=32; off; off>>=1) mx = fmaxf(mx, __shfl_xor(mx, off));
    float e0 = fexp(x0-mx), e1 = fexp(x1-mx);
    float sm = e0+e1;
#pragma unroll
    for (int off=32; off; off>>=1) sm += __shfl_xor(sm, off);
    float inv = 1.0f/sm;
    float wg0 = g*e0*inv + (1.f-g)*w_arr[l];
    float wg1 = g*e1*inv + (1.f-g)*w_arr[l+64];
    float up0 = __shfl(wg0, (l+1)&63);
    float w1f = __shfl(wg1, 0);
    float plus0 = (l==63) ? w1f : up0;
    float dn0 = __shfl(wg0, (l-1)&63);
    float w1b = __shfl(wg1, 63);
    float minus0 = (l==0) ? w1b : dn0;
    float up1 = __shfl(wg1, (l+1)&63);
    float w0f = __shfl(wg0, 0);
    float plus1 = (l==63) ? w0f : up1;
    float dn1 = __shfl(wg1, (l-1)&63);
    float w0b = __shfl(wg0, 63);
    float minus1 = (l==0) ? w0b : dn1;
    float ws0 = s0*plus0 + s1*wg0 + s2*minus0;
    float ws1 = s0*plus1 + s1*wg1 + s2*minus1;
    float wp0 = fpow_(fmaxf(ws0, 1e-12f), gamma);
    float wp1 = fpow_(fmaxf(ws1, 1e-12f), gamma);
    float tot = wp0+wp1;
#pragma unroll
    for (int off=32; off; off>>=1) tot += __shfl_xor(tot, off);
    float invt = 1.0f/tot;
    w_arr[l]    = wp0*invt;
    w_arr[l+64] = wp1*invt;
  }
  __syncthreads();
}

extern "C" __global__ __launch_bounds__(TPB, 1)
void ntm_coop(const float* __restrict__ inputs, const float* __restrict__ W_lstm,
              const float* __restrict__ b_lstm, const float* __restrict__ W_int,
              const float* __restrict__ b_int, const float* __restrict__ W_out,
              const float* __restrict__ b_out, float* __restrict__ out,
              float* __restrict__ wsf)
{
  __shared__ float mem_s[NN*NM];          // 32 KB persistent memory (batch blocks)
  __shared__ float wr_s[NN], ww_s[NN];
  __shared__ float scal_s[14];
  __shared__ USH u;

  int*    cbase   = (int*)wsf;            // cnt_g[q] @ [q*16] (q<8); cnt_w @ [256]
  int*    flags_r = (int*)wsf + 1024;     // 32 lines: r(s) posted (era s+1)
  __half* hT16    = (__half*)(wsf + 8192);   // [par][batch][unit] fp16: 2*512*32 halves
  float*  rT      = wsf + 8192 + 16384;   // [batch][m] 32*64
  float*  WrT     = rT + NB*NM;           // [col][k] fp32 2048*64
  unsigned short* WintT16 = (unsigned short*)(WrT + ZD*64);  // [c][k] 268*512 fp16
  unsigned short* WoutT16 = WintT16 + PD*NH;                 // [c][k] 64*576 fp16

  const int t   = threadIdx.x;
  const int bid = blockIdx.x;
  const bool isB = (bid < NB);

  // ---- one-time weight transposes/converts (coherent stores; cnt_w barrier) ----
  {
    int gid = bid*TPB + t;
    for (int idx = gid; idx < PD*NH; idx += GBLK*TPB) {
      int c = idx >> 9, k = idx & 511;
      cstoreh(&WintT16[idx],
              __builtin_bit_cast(unsigned short, __float2half(W_int[(size_t)k*PD + c])));
    }
    for (int idx = gid; idx < NO*576; idx += GBLK*TPB) {
      int c = idx / 576, k = idx - c*576;
      cstoreh(&WoutT16[idx],
              __builtin_bit_cast(unsigned short, __float2half(W_out[(size_t)k*NO + c])));
    }
    for (int idx = gid; idx < ZD*64; idx += GBLK*TPB) {
      int c = idx >> 6, k = idx & 63;
      cstoref(&WrT[idx], W_lstm[(size_t)(64 + k)*ZD + c]);
    }
  }
  postCnt(&cbase[256]);                   // one-time: converts drained
  waitCnt(&cbase[256], GBLK);             // one-time: all converts visible

  if (!isB) {
    // ==================== GEMM role (128 blocks) ====================
    const int gb   = bid - NB;
    const int pb_  = t & 31;               // batch lane for GEMM
    const int gate = (t >> 5) & 3;
    const int kp   = t >> 7;               // k-part 0..3
    const int j0   = ((gb & 7) << 6) + ((gb >> 3) * UPB);  // XCD-contiguous cols
    const int colg = gate*NH + j0;
    const int pj   = t >> 5;               // pointwise unit (t<128)
    const int pw   = t & 31;               // pointwise batch
    const int q_g  = gb & 7;               // h-group (16 blocks each)
    float c_reg = 0.f;
    __syncthreads();

    for (int step = 0; step < NS; ++step) {
      const __half* h16_prev = hT16 + (size_t)((step & 1) ^ 1)*NH*NB;
      __half*       h16_cur  = hT16 + (size_t)(step & 1)*NH*NB;

      // ---- all h(s-1) visible: 8 group counters, 8 lanes poll 1 line each ----
      if (step) {
        if (t < 8) {
          const int tgt = 16*step;
          while (cloadi(&cbase[t*16]) < tgt) __builtin_amdgcn_s_sleep(1);
        }
        __syncthreads();
      }

      // ---- stage x(s) and h(s-1) ----
      { int sb = t >> 4, k4 = (t & 15) * 4;
        float4 xv = *(const float4*)(inputs + ((size_t)sb*NS + step)*NI + k4);
        *(float4*)&u.p1.inT[sb*ST + k4] = xv; }
      if (step == 0) {
#pragma unroll
        for (int i = 0; i < 8; ++i) {
          int q = t + 512*i; int b_ = q >> 7, u_ = (q & 127) * 4;
          *(float4*)&u.p1.inT[b_*ST + 64 + u_] = make_float4(0.f,0.f,0.f,0.f);
        }
      } else {
#pragma unroll
        for (int i = 0; i < 8; ++i) {
          int q = t + 512*i; int b_ = q >> 7, u_ = (q & 127) * 4;
          unsigned long long v = cload8(h16_prev + b_*NH + u_);
          float o[4]; unpackh4(v, o);
          *(float4*)&u.p1.inT[b_*ST + 64 + u_] = make_float4(o[0],o[1],o[2],o[3]);
        }
      }
      __syncthreads();

      // ---- z_xh(s): 16 cols x 32 batches ----
      float a0=0.f, a1=0.f, a2=0.f, a3=0.f;
      {
        const float* xr = &u.p1.inT[pb_*ST + kp*16];
        const float* Wp = W_lstm + (size_t)(kp*16)*ZD + colg;
#pragma unroll
        for (int k4 = 0; k4 < 16; k4 += 4) {
          float4 x = *(const float4*)&xr[k4];
          float4 w0 = *(const float4*)(Wp + (size_t)(k4+0)*ZD);
          float4 w1 = *(const float4*)(Wp + (size_t)(k4+1)*ZD);
          float4 w2 = *(const float4*)(Wp + (size_t)(k4+2)*ZD);
          float4 w3 = *(const float4*)(Wp + (size_t)(k4+3)*ZD);
          a0 = fmaf(x.x, w0.x, a0); a1 = fmaf(x.x, w0.y, a1);
          a2 = fmaf(x.x, w0.z, a2); a3 = fmaf(x.x, w0.w, a3);
          a0 = fmaf(x.y, w1.x, a0); a1 = fmaf(x.y, w1.y, a1);
          a2 = fmaf(x.y, w1.z, a2); a3 = fmaf(x.y, w1.w, a3);
          a0 = fmaf(x.z, w2.x, a0); a1 = fmaf(x.z, w2.y, a1);
          a2 = fmaf(x.z, w2.z, a2); a3 = fmaf(x.z, w2.w, a3);
          a0 = fmaf(x.w, w3.x, a0); a1 = fmaf(x.w, w3.y, a1);
          a2 = fmaf(x.w, w3.z, a2); a3 = fmaf(x.w, w3.w, a3);
        }
        const float* hr = &u.p1.inT[pb_*ST + 64 + kp*128];
        const float* Wh = W_lstm + (size_t)(128 + kp*128)*ZD + colg;
#pragma unroll 4
        for (int k4 = 0; k4 < 128; k4 += 4) {
          float4 x = *(const float4*)&hr[k4];
          float4 w0 = *(const float4*)(Wh + (size_t)(k4+0)*ZD);
          float4 w1 = *(const float4*)(Wh + (size_t)(k4+1)*ZD);
          float4 w2 = *(const float4*)(Wh + (size_t)(k4+2)*ZD);
          float4 w3 = *(const float4*)(Wh + (size_t)(k4+3)*ZD);
          a0 = fmaf(x.x, w0.x, a0); a1 = fmaf(x.x, w0.y, a1);
          a2 = fmaf(x.x, w0.z, a2); a3 = fmaf(x.x, w0.w, a3);
          a0 = fmaf(x.y, w1.x, a0); a1 = fmaf(x.y, w1.y, a1);
          a2 = fmaf(x.y, w1.z, a2); a3 = fmaf(x.y, w1.w, a3);
          a0 = fmaf(x.z, w2.x, a0); a1 = fmaf(x.z, w2.y, a1);
          a2 = fmaf(x.z, w2.z, a2); a3 = fmaf(x.z, w2.w, a3);
          a0 = fmaf(x.w, w3.x, a0); a1 = fmaf(x.w, w3.y, a1);
          a2 = fmaf(x.w, w3.z, a2); a3 = fmaf(x.w, w3.w, a3);
        }
        if (step == 0) {   // bake z_r(0) from r_init = 0.01
          const float* Wr0 = W_lstm + (size_t)(64 + kp*16)*ZD + colg;
#pragma unroll
          for (int k = 0; k < 16; ++k) {
            float4 w = *(const float4*)(Wr0 + (size_t)k*ZD);
            a0 = fmaf(0.01f, w.x, a0); a1 = fmaf(0.01f, w.y, a1);
            a2 = fmaf(0.01f, w.z, a2); a3 = fmaf(0.01f, w.w, a3);
          }
        }
      }
      { int base = (kp*16 + gate*4)*32 + pb_;
        u.p1.zpart[base]    = a0;
        u.p1.zpart[base+32] = a1;
        u.p1.zpart[base+64] = a2;
        u.p1.zpart[base+96] = a3; }

      // ---- wait r(s-1), stage to LDS ----
      if (step) {
        waitAll32(flags_r, step);
        { int e = 2*t; int bb = e >> 6, kk = e & 63;
          float2 v = cloadf2(rT + e);
          *(float2*)&u.p1.rs[bb*RS_ST + kk] = v;
          e += 1024; bb = e >> 6; kk = e & 63;
          v = cloadf2(rT + e);
          *(float2*)&u.p1.rs[bb*RS_ST + kk] = v; }
      }
      __syncthreads();

      // ---- pointwise: z = z_xh + z_r + bias -> c,h ----
      if (t < 128) {
        float zrv[4] = {0.f, 0.f, 0.f, 0.f};
        if (step) {
          const float* rr = &u.p1.rs[pw*RS_ST];
#pragma unroll
          for (int gt = 0; gt < 4; ++gt) {
            const float* Wc = WrT + (size_t)(gt*NH + j0 + pj)*64;
            float acc = 0.f;
#pragma unroll
            for (int k = 0; k < 64; k += 4) {
              float4 w = *(const float4*)&Wc[k];
              acc = fmaf(rr[k],   w.x, acc);
              acc = fmaf(rr[k+1], w.y, acc);
              acc = fmaf(rr[k+2], w.z, acc);
              acc = fmaf(rr[k+3], w.w, acc);
            }
            zrv[gt] = acc;
          }
        }
        float zv[4];
#pragma unroll
        for (int gt = 0; gt < 4; ++gt) {
          int ci = gt*4 + pj;
          zv[gt] = u.p1.zpart[ci*32 + pw] + u.p1.zpart[(16+ci)*32 + pw]
                 + u.p1.zpart[(32+ci)*32 + pw] + u.p1.zpart[(48+ci)*32 + pw]
                 + zrv[gt] + b_lstm[gt*NH + j0 + pj];
        }
        float cn = sigm(zv[1])*c_reg + sigm(zv[0])*ftanh(zv[2]);
        c_reg = cn;
        u.p1.hx[pj*33 + pw] = sigm(zv[3])*ftanh(cn);
      }
      __syncthreads();
      if (t < 32) {   // pack 4 units -> one 8B fp16 store per batch row
        unsigned long long v = packh4(u.p1.hx[t], u.p1.hx[33+t],
                                      u.p1.hx[66+t], u.p1.hx[99+t]);
        cstore8(h16_cur + t*NH + j0, v);
      }
      postCnt(&cbase[q_g*16]);            // h slice posted -> group counter
    }
  } else {
    // ==================== batch role (32 blocks) ====================
    const int b = bid;
    for (int i = t; i < NN*NM; i += TPB) mem_s[i] = 0.01f;
    if (t < NN) { wr_s[t] = (t==0)?1.f:0.f; ww_s[t] = (t==0)?1.f:0.f; }
    __syncthreads();

    for (int step = 0; step < NS; ++step) {
      const int era = step + 1;
      const __half* h16_cur = hT16 + (size_t)(step & 1)*NH*NB;

      // ---- wait all h(s): 8 group counters ----
      if (t < 8) {
        const int tgt = 16*era;
        while (cloadi(&cbase[t*16]) < tgt) __builtin_amdgcn_s_sleep(1);
      }
      __syncthreads();

      // ---- read own h row (coalesced coherent, 1 KB) ----
      if (t < 128) {
        unsigned long long v = cload8(h16_cur + b*NH + 4*t);
        float o[4]; unpackh4(v, o);
        *(float4*)&u.p3.h[4*t] = make_float4(o[0],o[1],o[2],o[3]);
      }
      __syncthreads();

      // ---- p = h @ W_int + b_int (fp16 weights, plain loads, XCD-L2 resident) ----
      {
        int c = t >> 1, kh = t & 1;
        const unsigned long long* Wc =
            (const unsigned long long*)(WintT16 + (size_t)c*512 + kh*256);
        const float* hh = u.p3.h + kh*256;
        float pacc = 0.f;
#pragma unroll 8
        for (int k = 0; k < 256; k += 4) {
          float o[4]; unpackh4(Wc[k >> 2], o);
          pacc = fmaf(hh[k],   o[0], pacc);
          pacc = fmaf(hh[k+1], o[1], pacc);
          pacc = fmaf(hh[k+2], o[2], pacc);
          pacc = fmaf(hh[k+3], o[3], pacc);
        }
        u.p3.pp[t] = pacc;
        if (t < 24) {
          int id = 512 + t; int c2 = id >> 1; int k2 = id & 1;
          const unsigned long long* Wc2 =
              (const unsigned long long*)(WintT16 + (size_t)c2*512 + k2*256);
          const float* hh2 = u.p3.h + k2*256;
          float pa2 = 0.f;
#pragma unroll 8
          for (int k = 0; k < 256; k += 4) {
            float o[4]; unpackh4(Wc2[k >> 2], o);
            pa2 = fmaf(hh2[k],   o[0], pa2);
            pa2 = fmaf(hh2[k+1], o[1], pa2);
            pa2 = fmaf(hh2[k+2], o[2], pa2);
            pa2 = fmaf(hh2[k+3], o[3], pa2);
          }
          u.p3.pp[id] = pa2;
        }
      }
      __syncthreads();
      if (t < PD) u.p3.p[t] = u.p3.pp[2*t] + u.p3.pp[2*t+1] + b_int[t];
      __syncthreads();

      // head params
      if (t < NM) {
        float rk = ftanh(u.p3.p[t]);
        float wk = ftanh(u.p3.p[70+t]);
        u.p3.rk[t] = rk; u.p3.wk[t] = wk;
        u.p3.e[t] = sigm(u.p3.p[140+t]);
        u.p3.a[t] = ftanh(u.p3.p[204+t]);
        float sr = rk*rk, sw = wk*wk;
#pragma unroll
        for (int off=32; off; off>>=1){ sr += __shfl_xor(sr,off); sw += __shfl_xor(sw,off); }
        if (t == 0) { scal_s[0] = sqrtf(sr); scal_s[7] = sqrtf(sw); }
      }
      if (t == 64) {
        scal_s[1] = softplus_(u.p3.p[64]);
        scal_s[2] = sigm(u.p3.p[65]);
        float a0=u.p3.p[66], a1=u.p3.p[67], a2=u.p3.p[68];
        float m = fmaxf(a0,fmaxf(a1,a2));
        float e0=fexp(a0-m), e1=fexp(a1-m), e2=fexp(a2-m);
        float s = e0+e1+e2;
        scal_s[3]=e0/s; scal_s[4]=e1/s; scal_s[5]=e2/s;
        scal_s[6] = 1.f + softplus_(u.p3.p[69]);
      }
      if (t == 128) {
        scal_s[8]  = softplus_(u.p3.p[134]);
        scal_s[9]  = sigm(u.p3.p[135]);
        float a0=u.p3.p[136], a1=u.p3.p[137], a2=u.p3.p[138];
        float m = fmaxf(a0,fmaxf(a1,a2));
        float e0=fexp(a0-m), e1=fexp(a1-m), e2=fexp(a2-m);
        float s = e0+e1+e2;
        scal_s[10]=e0/s; scal_s[11]=e1/s; scal_s[12]=e2/s;
        scal_s[13] = 1.f + softplus_(u.p3.p[139]);
      }
      __syncthreads();

      address_head(t, u.p3.wk, &scal_s[7], ww_s, mem_s, u.p3.sim);

      {  // erase + add
        int n = t >> 2, sub = t & 3;
        int cn = (n & 7) << 2;
        float w = ww_s[n];
#pragma unroll
        for (int i = 0; i < 16; i += 4) {
          int m = sub*16 + i;
          float* mp = &mem_s[n*NM + (m ^ cn)];
          float4 mv = *(float4*)mp;
          float4 ev = *(const float4*)&u.p3.e[m];
          float4 av = *(const float4*)&u.p3.a[m];
          mv.x = mv.x*(1.f - w*ev.x) + w*av.x;
          mv.y = mv.y*(1.f - w*ev.y) + w*av.y;
          mv.z = mv.z*(1.f - w*ev.z) + w*av.z;
          mv.w = mv.w*(1.f - w*ev.w) + w*av.w;
          *(float4*)mp = mv;
        }
      }
      __syncthreads();

      address_head(t, u.p3.rk, &scal_s[0], wr_s, mem_s, u.p3.sim);

      {  // r = w_r @ mem
        int part = t >> 6, m = t & 63;
        float racc = 0.f;
#pragma unroll
        for (int nn = 0; nn < 16; ++nn) {
          int n = part*16 + nn;
          racc = fmaf(wr_s[n], mem_s[n*NM + (m ^ ((n&7)<<2))], racc);
        }
        u.p3.red[part*64 + m] = racc;
      }
      __syncthreads();
      if (t < NM) {
        float rv = 0.f;
#pragma unroll
        for (int pq = 0; pq < 8; ++pq) rv += u.p3.red[pq*64 + t];
        u.p3.r[t] = rv;
        cstoref(&rT[b*NM + t], rv);
      }
      postFlag(flags_r, b, era);          // r(s) visible -> GEMM can proceed

      // ---- off-path: out(s) = [h, r] @ W_out + b_out (fp16 weights) ----
      {
        int part = t >> 6, c = t & 63;
        const unsigned long long* Wc =
            (const unsigned long long*)(WoutT16 + (size_t)c*576 + part*72);
        float oacc = 0.f;
        int k0 = part*72;
#pragma unroll
        for (int kk = 0; kk < 72; kk += 4) {
          float o[4]; unpackh4(Wc[kk >> 2], o);
          int k = k0 + kk;
          float v0 = (k   < NH) ? u.p3.h[k]   : u.p3.r[k-NH];
          float v1 = (k+1 < NH) ? u.p3.h[k+1] : u.p3.r[k+1-NH];
          float v2 = (k+2 < NH) ? u.p3.h[k+2] : u.p3.r[k+2-NH];
          float v3 = (k+3 < NH) ? u.p3.h[k+3] : u.p3.r[k+3-NH];
          oacc = fmaf(v0, o[0], oacc);
          oacc = fmaf(v1, o[1], oacc);
          oacc = fmaf(v2, o[2], oacc);
          oacc = fmaf(v3, o[3], oacc);
        }
        u.p3.red[part*64 + c] = oacc;
      }
      __syncthreads();
      if (t < NO) {
        float ov = b_out[t];
#pragma unroll
        for (int pq = 0; pq < 8; ++pq) ov += u.p3.red[pq*64 + t];
        out[(size_t)b*NS*NO + (size_t)step*NO + t] = ov;
      }
      __syncthreads();
    }
  }
}

extern "C" void kernel_launch(void* const* d_in, const int* in_sizes, int n_in,
                              void* d_out, int out_size, void* d_ws, size_t ws_size,
                              hipStream_t stream) {
  const float* inputs = (const float*)d_in[0];
  const float* W_lstm = (const float*)d_in[1];
  const float* b_lstm = (const float*)d_in[2];
  const float* W_int  = (const float*)d_in[3];
  const float* b_int  = (const float*)d_in[4];
  const float* W_out  = (const float*)d_in[5];
  const float* b_out  = (const float*)d_in[6];
  float* outp = (float*)d_out;
  float* wsp  = (float*)d_ws;

  hipMemsetAsync(d_ws, 0, 32768, stream);   // zero cnt_g/cnt_w/flags_r each launch

  void* args[] = { (void*)&inputs, (void*)&W_lstm, (void*)&b_lstm,
                   (void*)&W_int, (void*)&b_int, (void*)&W_out, (void*)&b_out,
                   (void*)&outp, (void*)&wsp };
  hipLaunchCooperativeKernel((const void*)ntm_coop, dim3(GBLK), dim3(TPB),
                             args, 0, stream);
}

// Round 18
// 5261.039 us; speedup vs baseline: 1.2999x; 1.0322x over previous
//
#include <hip/hip_runtime.h>
#include <hip/hip_fp16.h>
#include <math.h>

#define NI 64
#define NO 64
#define NH 512
#define NM 64
#define NN 128
#define NB 32
#define NS 256
#define ZD 2048
#define PD 268
#define NG 128         // GEMM blocks
#define GBLK 160       // 32 batch + 128 GEMM
#define TPB 512
#define UPB 4          // hidden units per GEMM block
#define ST 580         // LDS stride for inT rows [b][k]
#define RS_ST 68       // padded stride for r tile (68%32==4)

// ---- fast transcendentals ----
__device__ __forceinline__ float fexp(float x){ return __expf(x); }
__device__ __forceinline__ float sigm(float x){ return 1.0f/(1.0f+__expf(-x)); }
__device__ __forceinline__ float ftanh(float x){
  float e = __expf(2.f*x);
  return (x > 10.f) ? 1.f : (x < -10.f) ? -1.f : (e - 1.f)/(e + 1.f);
}
__device__ __forceinline__ float softplus_(float x){
  return (x > 15.f) ? x : __logf(1.f + __expf(x));
}
__device__ __forceinline__ float fpow_(float x, float g){   // x>0
  return __expf(g*__logf(x));
}

// ---- packed fp16 dot (v_dot2_f32_f16) with fallback ----
typedef _Float16 h2_t __attribute__((ext_vector_type(2)));
#if defined(__has_builtin)
#if __has_builtin(__builtin_amdgcn_fdot2)
#define HAS_FDOT2 1
#endif
#endif
__device__ __forceinline__ float fdot2_(unsigned int w, unsigned int h, float acc){
#ifdef HAS_FDOT2
  return __builtin_amdgcn_fdot2(__builtin_bit_cast(h2_t, w),
                                __builtin_bit_cast(h2_t, h), acc, false);
#else
  float w0 = __half2float(__builtin_bit_cast(__half, (unsigned short)(w      )));
  float w1 = __half2float(__builtin_bit_cast(__half, (unsigned short)(w >> 16)));
  float h0 = __half2float(__builtin_bit_cast(__half, (unsigned short)(h      )));
  float h1 = __half2float(__builtin_bit_cast(__half, (unsigned short)(h >> 16)));
  return fmaf(w1, h1, fmaf(w0, h0, acc));
#endif
}

// ---- coherent (cross-XCD) access helpers: relaxed system-scope = sc0 sc1 ----
__device__ __forceinline__ float cloadf(const float* p){
  return __hip_atomic_load(p, __ATOMIC_RELAXED, __HIP_MEMORY_SCOPE_SYSTEM);
}
__device__ __forceinline__ void cstoref(float* p, float v){
  __hip_atomic_store(p, v, __ATOMIC_RELAXED, __HIP_MEMORY_SCOPE_SYSTEM);
}
__device__ __forceinline__ float2 cloadf2(const float* p){
  unsigned long long u = __hip_atomic_load((const unsigned long long*)p,
                                           __ATOMIC_RELAXED, __HIP_MEMORY_SCOPE_SYSTEM);
  return __builtin_bit_cast(float2, u);
}
__device__ __forceinline__ unsigned long long cload8(const void* p){
  return __hip_atomic_load((const unsigned long long*)p,
                           __ATOMIC_RELAXED, __HIP_MEMORY_SCOPE_SYSTEM);
}
__device__ __forceinline__ void cstore8(void* p, unsigned long long v){
  __hip_atomic_store((unsigned long long*)p, v,
                     __ATOMIC_RELAXED, __HIP_MEMORY_SCOPE_SYSTEM);
}
__device__ __forceinline__ int cloadi(const int* p){
  return __hip_atomic_load(p, __ATOMIC_RELAXED, __HIP_MEMORY_SCOPE_SYSTEM);
}
__device__ __forceinline__ void cstorei(int* p, int v){
  __hip_atomic_store(p, v, __ATOMIC_RELAXED, __HIP_MEMORY_SCOPE_SYSTEM);
}
__device__ __forceinline__ void caddi(int* p){
  __hip_atomic_fetch_add(p, 1, __ATOMIC_RELAXED, __HIP_MEMORY_SCOPE_SYSTEM);
}
__device__ __forceinline__ void cstoreh(unsigned short* p, unsigned short v){
  __hip_atomic_store(p, v, __ATOMIC_RELAXED, __HIP_MEMORY_SCOPE_SYSTEM);
}

// fp16 pack/unpack
__device__ __forceinline__ unsigned long long packh4(float a, float b, float c, float d){
  unsigned short u0 = __builtin_bit_cast(unsigned short, __float2half(a));
  unsigned short u1 = __builtin_bit_cast(unsigned short, __float2half(b));
  unsigned short u2 = __builtin_bit_cast(unsigned short, __float2half(c));
  unsigned short u3 = __builtin_bit_cast(unsigned short, __float2half(d));
  return (unsigned long long)u0 | ((unsigned long long)u1 << 16)
       | ((unsigned long long)u2 << 32) | ((unsigned long long)u3 << 48);
}
__device__ __forceinline__ void unpackh4(unsigned long long v, float* o){
  o[0] = __half2float(__builtin_bit_cast(__half, (unsigned short)(v      )));
  o[1] = __half2float(__builtin_bit_cast(__half, (unsigned short)(v >> 16)));
  o[2] = __half2float(__builtin_bit_cast(__half, (unsigned short)(v >> 32)));
  o[3] = __half2float(__builtin_bit_cast(__half, (unsigned short)(v >> 48)));
}

// ---- barrier primitives ----
__device__ __forceinline__ void postFlag(int* flags, int idx, int era){
  __syncthreads();                        // payload stores drained (vmcnt0)
  if (threadIdx.x == 0) cstorei(&flags[idx*16], era);
}
__device__ __forceinline__ void waitAll32(const int* flags, int era){
  if (threadIdx.x < 32) {
    while (cloadi(&flags[(int)threadIdx.x*16]) < era)
      __builtin_amdgcn_s_sleep(1);
  }
  __syncthreads();
}
__device__ __forceinline__ void postCnt(int* c){
  __syncthreads();                        // payload stores drained (vmcnt0)
  if (threadIdx.x == 0) caddi(c);
}
__device__ __forceinline__ void waitCnt(const int* c, int target){
  if (threadIdx.x == 0) {
    while (cloadi(c) < target) __builtin_amdgcn_s_sleep(2);
  }
  __syncthreads();
}

struct P1S { float inT[NB*ST]; float zpart[4*16*32]; float rs[NB*RS_ST]; float hx[4*33]; };
struct P3S { float h[NH]; unsigned long long h16[128]; float pp[544]; float p[PD+4];
             float rk[NM], wk[NM], e[NM], a[NM];
             float sim[NN]; float red[8*64]; float r[NM]; };
union  USH { P1S p1; P3S p3; };

// content+location addressing; 512 threads; mem_s XOR-swizzled:
// logical mem[n][m] at float offset n*64 + (m ^ ((n&7)<<2)).
__device__ void address_head(int t, const float* __restrict__ ks,
                             const float* __restrict__ scal,
                             float* __restrict__ w_arr,
                             const float* __restrict__ mem_s,
                             float* __restrict__ sim_s)
{
  {
    int n = t >> 2, sub = t & 3;
    int cn = (n & 7) << 2;
    float dot = 0.f, sq = 0.f;
#pragma unroll
    for (int i = 0; i < 16; i += 4) {
      int m = sub*16 + i;
      float4 mv = *(const float4*)&mem_s[n*NM + (m ^ cn)];
      float4 kv = *(const float4*)&ks[m];
      dot = fmaf(kv.x, mv.x, dot); dot = fmaf(kv.y, mv.y, dot);
      dot = fmaf(kv.z, mv.z, dot); dot = fmaf(kv.w, mv.w, dot);
      sq  = fmaf(mv.x, mv.x, sq);  sq  = fmaf(mv.y, mv.y, sq);
      sq  = fmaf(mv.z, mv.z, sq);  sq  = fmaf(mv.w, mv.w, sq);
    }
    dot += __shfl_xor(dot, 1); sq += __shfl_xor(sq, 1);
    dot += __shfl_xor(dot, 2); sq += __shfl_xor(sq, 2);
    if (sub == 0) sim_s[n] = dot / (scal[0]*sqrtf(sq) + 1e-8f);
  }
  __syncthreads();
  if (t < 64) {   // wave 0: softmax+gate+shift+sharpen; lane l owns rows l, l+64
    int l = t;
    float beta = scal[1], g = scal[2], s0 = scal[3], s1 = scal[4], s2 = scal[5], gamma = scal[6];
    float x0 = beta*sim_s[l], x1 = beta*sim_s[l+64];
    float mx = fmaxf(x0, x1);
#pragma unroll
    for (int off=32; off; off>>=1) mx = fmaxf(mx, __shfl_xor(mx, off));
    float e0 = fexp(x0-mx), e1 = fexp(x1-mx);
    float sm = e0+e1;
#pragma unroll
    for (int off=32; off; off>>=1) sm += __shfl_xor(sm, off);
    float inv = 1.0f/sm;
    float wg0 = g*e0*inv + (1.f-g)*w_arr[l];
    float wg1 = g*e1*inv + (1.f-g)*w_arr[l+64];
    float up0 = __shfl(wg0, (l+1)&63);
    float w1f = __shfl(wg1, 0);
    float plus0 = (l==63) ? w1f : up0;
    float dn0 = __shfl(wg0, (l-1)&63);
    float w1b = __shfl(wg1, 63);
    float minus0 = (l==0) ? w1b : dn0;
    float up1 = __shfl(wg1, (l+1)&63);
    float w0f = __shfl(wg0, 0);
    float plus1 = (l==63) ? w0f : up1;
    float dn1 = __shfl(wg1, (l-1)&63);
    float w0b = __shfl(wg0, 63);
    float minus1 = (l==0) ? w0b : dn1;
    float ws0 = s0*plus0 + s1*wg0 + s2*minus0;
    float ws1 = s0*plus1 + s1*wg1 + s2*minus1;
    float wp0 = fpow_(fmaxf(ws0, 1e-12f), gamma);
    float wp1 = fpow_(fmaxf(ws1, 1e-12f), gamma);
    float tot = wp0+wp1;
#pragma unroll
    for (int off=32; off; off>>=1) tot += __shfl_xor(tot, off);
    float invt = 1.0f/tot;
    w_arr[l]    = wp0*invt;
    w_arr[l+64] = wp1*invt;
  }
  __syncthreads();
}

extern "C" __global__ __launch_bounds__(TPB, 1)
void ntm_coop(const float* __restrict__ inputs, const float* __restrict__ W_lstm,
              const float* __restrict__ b_lstm, const float* __restrict__ W_int,
              const float* __restrict__ b_int, const float* __restrict__ W_out,
              const float* __restrict__ b_out, float* __restrict__ out,
              float* __restrict__ wsf)
{
  __shared__ float mem_s[NN*NM];          // 32 KB persistent memory (batch blocks)
  __shared__ float wr_s[NN], ww_s[NN];
  __shared__ float scal_s[14];
  __shared__ USH u;

  int*    cbase   = (int*)wsf;            // cnt_g[q] @ [q*16] (q<8); cnt_w @ [256]
  int*    flags_r = (int*)wsf + 1024;     // 32 lines: r(s) posted (era s+1)
  __half* hT16    = (__half*)(wsf + 8192);   // [par][batch][unit] fp16: 2*512*32 halves
  float*  rT      = wsf + 8192 + 16384;   // [batch][m] 32*64
  float*  WrT     = rT + NB*NM;           // [col][k] fp32 2048*64
  unsigned short* WintT16 = (unsigned short*)(WrT + ZD*64);  // [c][k] 268*512 fp16
  unsigned short* WoutT16 = WintT16 + PD*NH;                 // [c][k] 64*576 fp16

  const int t   = threadIdx.x;
  const int bid = blockIdx.x;
  const bool isB = (bid < NB);

  // ---- one-time weight transposes/converts (coherent stores; cnt_w barrier) ----
  {
    int gid = bid*TPB + t;
    for (int idx = gid; idx < PD*NH; idx += GBLK*TPB) {
      int c = idx >> 9, k = idx & 511;
      cstoreh(&WintT16[idx],
              __builtin_bit_cast(unsigned short, __float2half(W_int[(size_t)k*PD + c])));
    }
    for (int idx = gid; idx < NO*576; idx += GBLK*TPB) {
      int c = idx / 576, k = idx - c*576;
      cstoreh(&WoutT16[idx],
              __builtin_bit_cast(unsigned short, __float2half(W_out[(size_t)k*NO + c])));
    }
    for (int idx = gid; idx < ZD*64; idx += GBLK*TPB) {
      int c = idx >> 6, k = idx & 63;
      cstoref(&WrT[idx], W_lstm[(size_t)(64 + k)*ZD + c]);
    }
  }
  postCnt(&cbase[256]);                   // one-time: converts drained
  waitCnt(&cbase[256], GBLK);             // one-time: all converts visible

  if (!isB) {
    // ==================== GEMM role (128 blocks) ====================
    const int gb   = bid - NB;
    const int pb_  = t & 31;               // batch lane for GEMM
    const int gate = (t >> 5) & 3;
    const int kp   = t >> 7;               // k-part 0..3
    const int j0   = ((gb & 7) << 6) + ((gb >> 3) * UPB);  // XCD-contiguous cols
    const int colg = gate*NH + j0;
    const int pj   = t >> 5;               // pointwise unit (t<128)
    const int pw   = t & 31;               // pointwise batch
    const int q_g  = gb & 7;               // h-group (16 blocks each)
    float c_reg = 0.f;
    __syncthreads();

    for (int step = 0; step < NS; ++step) {
      const __half* h16_prev = hT16 + (size_t)((step & 1) ^ 1)*NH*NB;
      __half*       h16_cur  = hT16 + (size_t)(step & 1)*NH*NB;

      // ---- all h(s-1) visible: 8 group counters, 8 lanes poll 1 line each ----
      if (step) {
        if (t < 8) {
          const int tgt = 16*step;
          while (cloadi(&cbase[t*16]) < tgt) __builtin_amdgcn_s_sleep(1);
        }
        __syncthreads();
      }

      // ---- stage x(s) and h(s-1) ----
      { int sb = t >> 4, k4 = (t & 15) * 4;
        float4 xv = *(const float4*)(inputs + ((size_t)sb*NS + step)*NI + k4);
        *(float4*)&u.p1.inT[sb*ST + k4] = xv; }
      if (step == 0) {
#pragma unroll
        for (int i = 0; i < 8; ++i) {
          int q = t + 512*i; int b_ = q >> 7, u_ = (q & 127) * 4;
          *(float4*)&u.p1.inT[b_*ST + 64 + u_] = make_float4(0.f,0.f,0.f,0.f);
        }
      } else {
#pragma unroll
        for (int i = 0; i < 8; ++i) {
          int q = t + 512*i; int b_ = q >> 7, u_ = (q & 127) * 4;
          unsigned long long v = cload8(h16_prev + b_*NH + u_);
          float o[4]; unpackh4(v, o);
          *(float4*)&u.p1.inT[b_*ST + 64 + u_] = make_float4(o[0],o[1],o[2],o[3]);
        }
      }
      __syncthreads();

      // ---- z_xh(s): 16 cols x 32 batches ----
      float a0=0.f, a1=0.f, a2=0.f, a3=0.f;
      {
        const float* xr = &u.p1.inT[pb_*ST + kp*16];
        const float* Wp = W_lstm + (size_t)(kp*16)*ZD + colg;
#pragma unroll
        for (int k4 = 0; k4 < 16; k4 += 4) {
          float4 x = *(const float4*)&xr[k4];
          float4 w0 = *(const float4*)(Wp + (size_t)(k4+0)*ZD);
          float4 w1 = *(const float4*)(Wp + (size_t)(k4+1)*ZD);
          float4 w2 = *(const float4*)(Wp + (size_t)(k4+2)*ZD);
          float4 w3 = *(const float4*)(Wp + (size_t)(k4+3)*ZD);
          a0 = fmaf(x.x, w0.x, a0); a1 = fmaf(x.x, w0.y, a1);
          a2 = fmaf(x.x, w0.z, a2); a3 = fmaf(x.x, w0.w, a3);
          a0 = fmaf(x.y, w1.x, a0); a1 = fmaf(x.y, w1.y, a1);
          a2 = fmaf(x.y, w1.z, a2); a3 = fmaf(x.y, w1.w, a3);
          a0 = fmaf(x.z, w2.x, a0); a1 = fmaf(x.z, w2.y, a1);
          a2 = fmaf(x.z, w2.z, a2); a3 = fmaf(x.z, w2.w, a3);
          a0 = fmaf(x.w, w3.x, a0); a1 = fmaf(x.w, w3.y, a1);
          a2 = fmaf(x.w, w3.z, a2); a3 = fmaf(x.w, w3.w, a3);
        }
        const float* hr = &u.p1.inT[pb_*ST + 64 + kp*128];
        const float* Wh = W_lstm + (size_t)(128 + kp*128)*ZD + colg;
#pragma unroll 4
        for (int k4 = 0; k4 < 128; k4 += 4) {
          float4 x = *(const float4*)&hr[k4];
          float4 w0 = *(const float4*)(Wh + (size_t)(k4+0)*ZD);
          float4 w1 = *(const float4*)(Wh + (size_t)(k4+1)*ZD);
          float4 w2 = *(const float4*)(Wh + (size_t)(k4+2)*ZD);
          float4 w3 = *(const float4*)(Wh + (size_t)(k4+3)*ZD);
          a0 = fmaf(x.x, w0.x, a0); a1 = fmaf(x.x, w0.y, a1);
          a2 = fmaf(x.x, w0.z, a2); a3 = fmaf(x.x, w0.w, a3);
          a0 = fmaf(x.y, w1.x, a0); a1 = fmaf(x.y, w1.y, a1);
          a2 = fmaf(x.y, w1.z, a2); a3 = fmaf(x.y, w1.w, a3);
          a0 = fmaf(x.z, w2.x, a0); a1 = fmaf(x.z, w2.y, a1);
          a2 = fmaf(x.z, w2.z, a2); a3 = fmaf(x.z, w2.w, a3);
          a0 = fmaf(x.w, w3.x, a0); a1 = fmaf(x.w, w3.y, a1);
          a2 = fmaf(x.w, w3.z, a2); a3 = fmaf(x.w, w3.w, a3);
        }
        if (step == 0) {   // bake z_r(0) from r_init = 0.01
          const float* Wr0 = W_lstm + (size_t)(64 + kp*16)*ZD + colg;
#pragma unroll
          for (int k = 0; k < 16; ++k) {
            float4 w = *(const float4*)(Wr0 + (size_t)k*ZD);
            a0 = fmaf(0.01f, w.x, a0); a1 = fmaf(0.01f, w.y, a1);
            a2 = fmaf(0.01f, w.z, a2); a3 = fmaf(0.01f, w.w, a3);
          }
        }
      }
      { int base = (kp*16 + gate*4)*32 + pb_;
        u.p1.zpart[base]    = a0;
        u.p1.zpart[base+32] = a1;
        u.p1.zpart[base+64] = a2;
        u.p1.zpart[base+96] = a3; }

      // ---- wait r(s-1), stage to LDS ----
      if (step) {
        waitAll32(flags_r, step);
        { int e = 2*t; int bb = e >> 6, kk = e & 63;
          float2 v = cloadf2(rT + e);
          *(float2*)&u.p1.rs[bb*RS_ST + kk] = v;
          e += 1024; bb = e >> 6; kk = e & 63;
          v = cloadf2(rT + e);
          *(float2*)&u.p1.rs[bb*RS_ST + kk] = v; }
      }
      __syncthreads();

      // ---- pointwise: z = z_xh + z_r + bias -> c,h ----
      if (t < 128) {
        float zrv[4] = {0.f, 0.f, 0.f, 0.f};
        if (step) {
          const float* rr = &u.p1.rs[pw*RS_ST];
#pragma unroll
          for (int gt = 0; gt < 4; ++gt) {
            const float* Wc = WrT + (size_t)(gt*NH + j0 + pj)*64;
            float acc = 0.f;
#pragma unroll
            for (int k = 0; k < 64; k += 4) {
              float4 w = *(const float4*)&Wc[k];
              acc = fmaf(rr[k],   w.x, acc);
              acc = fmaf(rr[k+1], w.y, acc);
              acc = fmaf(rr[k+2], w.z, acc);
              acc = fmaf(rr[k+3], w.w, acc);
            }
            zrv[gt] = acc;
          }
        }
        float zv[4];
#pragma unroll
        for (int gt = 0; gt < 4; ++gt) {
          int ci = gt*4 + pj;
          zv[gt] = u.p1.zpart[ci*32 + pw] + u.p1.zpart[(16+ci)*32 + pw]
                 + u.p1.zpart[(32+ci)*32 + pw] + u.p1.zpart[(48+ci)*32 + pw]
                 + zrv[gt] + b_lstm[gt*NH + j0 + pj];
        }
        float cn = sigm(zv[1])*c_reg + sigm(zv[0])*ftanh(zv[2]);
        c_reg = cn;
        u.p1.hx[pj*33 + pw] = sigm(zv[3])*ftanh(cn);
      }
      __syncthreads();
      if (t < 32) {   // pack 4 units -> one 8B fp16 store per batch row
        unsigned long long v = packh4(u.p1.hx[t], u.p1.hx[33+t],
                                      u.p1.hx[66+t], u.p1.hx[99+t]);
        cstore8(h16_cur + t*NH + j0, v);
      }
      postCnt(&cbase[q_g*16]);            // h slice posted -> group counter
    }
  } else {
    // ==================== batch role (32 blocks) ====================
    const int b = bid;
    for (int i = t; i < NN*NM; i += TPB) mem_s[i] = 0.01f;
    if (t < NN) { wr_s[t] = (t==0)?1.f:0.f; ww_s[t] = (t==0)?1.f:0.f; }
    __syncthreads();

    for (int step = 0; step < NS; ++step) {
      const int era = step + 1;
      const __half* h16_cur = hT16 + (size_t)(step & 1)*NH*NB;

      // ---- wait all h(s): 8 group counters ----
      if (t < 8) {
        const int tgt = 16*era;
        while (cloadi(&cbase[t*16]) < tgt) __builtin_amdgcn_s_sleep(1);
      }
      __syncthreads();

      // ---- read own h row (coalesced coherent, 1 KB): keep raw fp16 + floats ----
      if (t < 128) {
        unsigned long long v = cload8(h16_cur + b*NH + 4*t);
        u.p3.h16[t] = v;
        float o[4]; unpackh4(v, o);
        *(float4*)&u.p3.h[4*t] = make_float4(o[0],o[1],o[2],o[3]);
      }
      __syncthreads();

      // ---- p = h @ W_int + b_int (packed fp16 dot2; weights XCD-L2 resident) ----
      {
        int c = t >> 1, kh = t & 1;
        const unsigned long long* Wc =
            (const unsigned long long*)(WintT16 + (size_t)c*512 + kh*256);
        const unsigned long long* hh = u.p3.h16 + kh*64;   // 256 halves = 64 ull
        float pacc = 0.f;
#pragma unroll 8
        for (int k = 0; k < 64; ++k) {
          unsigned long long w = Wc[k], hv = hh[k];
          pacc = fdot2_((unsigned int)w,        (unsigned int)hv,        pacc);
          pacc = fdot2_((unsigned int)(w >> 32),(unsigned int)(hv >> 32), pacc);
        }
        u.p3.pp[t] = pacc;
        if (t < 24) {
          int id = 512 + t; int c2 = id >> 1; int k2 = id & 1;
          const unsigned long long* Wc2 =
              (const unsigned long long*)(WintT16 + (size_t)c2*512 + k2*256);
          const unsigned long long* hh2 = u.p3.h16 + k2*64;
          float pa2 = 0.f;
#pragma unroll 8
          for (int k = 0; k < 64; ++k) {
            unsigned long long w = Wc2[k], hv = hh2[k];
            pa2 = fdot2_((unsigned int)w,        (unsigned int)hv,        pa2);
            pa2 = fdot2_((unsigned int)(w >> 32),(unsigned int)(hv >> 32), pa2);
          }
          u.p3.pp[id] = pa2;
        }
      }
      __syncthreads();
      if (t < PD) u.p3.p[t] = u.p3.pp[2*t] + u.p3.pp[2*t+1] + b_int[t];
      __syncthreads();

      // head params
      if (t < NM) {
        float rk = ftanh(u.p3.p[t]);
        float wk = ftanh(u.p3.p[70+t]);
        u.p3.rk[t] = rk; u.p3.wk[t] = wk;
        u.p3.e[t] = sigm(u.p3.p[140+t]);
        u.p3.a[t] = ftanh(u.p3.p[204+t]);
        float sr = rk*rk, sw = wk*wk;
#pragma unroll
        for (int off=32; off; off>>=1){ sr += __shfl_xor(sr,off); sw += __shfl_xor(sw,off); }
        if (t == 0) { scal_s[0] = sqrtf(sr); scal_s[7] = sqrtf(sw); }
      }
      if (t == 64) {
        scal_s[1] = softplus_(u.p3.p[64]);
        scal_s[2] = sigm(u.p3.p[65]);
        float a0=u.p3.p[66], a1=u.p3.p[67], a2=u.p3.p[68];
        float m = fmaxf(a0,fmaxf(a1,a2));
        float e0=fexp(a0-m), e1=fexp(a1-m), e2=fexp(a2-m);
        float s = e0+e1+e2;
        scal_s[3]=e0/s; scal_s[4]=e1/s; scal_s[5]=e2/s;
        scal_s[6] = 1.f + softplus_(u.p3.p[69]);
      }
      if (t == 128) {
        scal_s[8]  = softplus_(u.p3.p[134]);
        scal_s[9]  = sigm(u.p3.p[135]);
        float a0=u.p3.p[136], a1=u.p3.p[137], a2=u.p3.p[138];
        float m = fmaxf(a0,fmaxf(a1,a2));
        float e0=fexp(a0-m), e1=fexp(a1-m), e2=fexp(a2-m);
        float s = e0+e1+e2;
        scal_s[10]=e0/s; scal_s[11]=e1/s; scal_s[12]=e2/s;
        scal_s[13] = 1.f + softplus_(u.p3.p[139]);
      }
      __syncthreads();

      address_head(t, u.p3.wk, &scal_s[7], ww_s, mem_s, u.p3.sim);

      {  // erase + add
        int n = t >> 2, sub = t & 3;
        int cn = (n & 7) << 2;
        float w = ww_s[n];
#pragma unroll
        for (int i = 0; i < 16; i += 4) {
          int m = sub*16 + i;
          float* mp = &mem_s[n*NM + (m ^ cn)];
          float4 mv = *(float4*)mp;
          float4 ev = *(const float4*)&u.p3.e[m];
          float4 av = *(const float4*)&u.p3.a[m];
          mv.x = mv.x*(1.f - w*ev.x) + w*av.x;
          mv.y = mv.y*(1.f - w*ev.y) + w*av.y;
          mv.z = mv.z*(1.f - w*ev.z) + w*av.z;
          mv.w = mv.w*(1.f - w*ev.w) + w*av.w;
          *(float4*)mp = mv;
        }
      }
      __syncthreads();

      address_head(t, u.p3.rk, &scal_s[0], wr_s, mem_s, u.p3.sim);

      {  // r = w_r @ mem
        int part = t >> 6, m = t & 63;
        float racc = 0.f;
#pragma unroll
        for (int nn = 0; nn < 16; ++nn) {
          int n = part*16 + nn;
          racc = fmaf(wr_s[n], mem_s[n*NM + (m ^ ((n&7)<<2))], racc);
        }
        u.p3.red[part*64 + m] = racc;
      }
      __syncthreads();
      if (t < NM) {
        float rv = 0.f;
#pragma unroll
        for (int pq = 0; pq < 8; ++pq) rv += u.p3.red[pq*64 + t];
        u.p3.r[t] = rv;
        cstoref(&rT[b*NM + t], rv);
      }
      postFlag(flags_r, b, era);          // r(s) visible -> GEMM can proceed

      // ---- off-path: out(s) = [h, r] @ W_out + b_out (fp16 weights) ----
      {
        int part = t >> 6, c = t & 63;
        const unsigned long long* Wc =
            (const unsigned long long*)(WoutT16 + (size_t)c*576 + part*72);
        float oacc = 0.f;
        int k0 = part*72;
#pragma unroll
        for (int kk = 0; kk < 72; kk += 4) {
          float o[4]; unpackh4(Wc[kk >> 2], o);
          int k = k0 + kk;
          float v0 = (k   < NH) ? u.p3.h[k]   : u.p3.r[k-NH];
          float v1 = (k+1 < NH) ? u.p3.h[k+1] : u.p3.r[k+1-NH];
          float v2 = (k+2 < NH) ? u.p3.h[k+2] : u.p3.r[k+2-NH];
          float v3 = (k+3 < NH) ? u.p3.h[k+3] : u.p3.r[k+3-NH];
          oacc = fmaf(v0, o[0], oacc);
          oacc = fmaf(v1, o[1], oacc);
          oacc = fmaf(v2, o[2], oacc);
          oacc = fmaf(v3, o[3], oacc);
        }
        u.p3.red[part*64 + c] = oacc;
      }
      __syncthreads();
      if (t < NO) {
        float ov = b_out[t];
#pragma unroll
        for (int pq = 0; pq < 8; ++pq) ov += u.p3.red[pq*64 + t];
        out[(size_t)b*NS*NO + (size_t)step*NO + t] = ov;
      }
      __syncthreads();
    }
  }
}

extern "C" void kernel_launch(void* const* d_in, const int* in_sizes, int n_in,
                              void* d_out, int out_size, void* d_ws, size_t ws_size,
                              hipStream_t stream) {
  const float* inputs = (const float*)d_in[0];
  const float* W_lstm = (const float*)d_in[1];
  const float* b_lstm = (const float*)d_in[2];
  const float* W_int  = (const float*)d_in[3];
  const float* b_int  = (const float*)d_in[4];
  const float* W_out  = (const float*)d_in[5];
  const float* b_out  = (const float*)d_in[6];
  float* outp = (float*)d_out;
  float* wsp  = (float*)d_ws;

  hipMemsetAsync(d_ws, 0, 32768, stream);   // zero cnt_g/cnt_w/flags_r each launch

  void* args[] = { (void*)&inputs, (void*)&W_lstm, (void*)&b_lstm,
                   (void*)&W_int, (void*)&b_int, (void*)&W_out, (void*)&b_out,
                   (void*)&outp, (void*)&wsp };
  hipLaunchCooperativeKernel((const void*)ntm_coop, dim3(GBLK), dim3(TPB),
                             args, 0, stream);
}